// Round 2
// baseline (112779.651 us; speedup 1.0000x reference)
//
#include <hip/hip_runtime.h>
#include <math.h>

// ============================================================================
// AR_Transcriber: conv stack -> FC -> 2-layer LSTM with argmax feedback.
// Round 2: ws-adaptive layout (no 358MB assumption) + cooperative LSTM launch.
//
// Path A (ws >= ~125.6 MB): aco | Z1a (conv scratch aliases Z1a) | states
// Path B (ws >= ~47.7 MB):  aco | A_chunk(1b) | Bf_chunk(1b) | states, LSTM
//                           computes the input dot from aco directly.
// ============================================================================

#define ACO_FL   6266880ull   // 8160*768
#define Z1A_FL  25067520ull   // 8160*3072
#define ST_FL      49168ull   // h1g(24576)+h2g(24576)+bar

__device__ __forceinline__ float sigf(float x) { return 1.0f / (1.0f + expf(-x)); }

__device__ __forceinline__ void gbar(unsigned* cnt, unsigned target) {
  __syncthreads();
  if (threadIdx.x == 0) {
    __threadfence();  // release: publish our stores device-wide
    __hip_atomic_fetch_add(cnt, 1u, __ATOMIC_ACQ_REL, __HIP_MEMORY_SCOPE_AGENT);
    while (__hip_atomic_load(cnt, __ATOMIC_ACQUIRE, __HIP_MEMORY_SCOPE_AGENT) < target) {
      __builtin_amdgcn_s_sleep(1);
    }
    __threadfence();  // acquire: see other blocks' stores
  }
  __syncthreads();
}

// ---------------------------------------------------------------------------
// K1: fused conv1+bn1+relu -> conv2+bn2+relu -> pool(1,2).
// Grid = nb*512 blocks; block = (local batch, t row). Writes A_c (local batch).
// ---------------------------------------------------------------------------
__global__ __launch_bounds__(256) void conv12_kernel(
    const float* __restrict__ mel,          // full mel, use b0+bl
    const float* __restrict__ c1w, const float* __restrict__ c1b,
    const float* __restrict__ bn1g, const float* __restrict__ bn1b,
    const float* __restrict__ bn1m, const float* __restrict__ bn1v,
    const float* __restrict__ c2w, const float* __restrict__ c2b,
    const float* __restrict__ bn2g, const float* __restrict__ bn2b,
    const float* __restrict__ bn2m, const float* __restrict__ bn2v,
    float* __restrict__ A, int b0)
{
  __shared__ float melS[5 * 232];      // rows t-2..t+2, cols -1..230
  __shared__ float x1S[12 * 3 * 232];  // conv1 out chunk
  __shared__ float wS[48 * 12 * 9];
  const int tid = threadIdx.x;
  const int bl = blockIdx.x >> 9;      // local batch
  const int b = b0 + bl;
  const int t = blockIdx.x & 511;

  for (int idx = tid; idx < 5 * 232; idx += 256) {
    int rr = idx / 232, cc = idx - rr * 232;
    int r = t - 2 + rr, w = cc - 1;
    float v = 0.f;
    if (r >= 0 && r < 512 && w >= 0 && w < 229) v = mel[(b * 512 + r) * 229 + w];
    melS[idx] = v;
  }

  float accA[22], accB[22];
#pragma unroll
  for (int i = 0; i < 22; ++i) { accA[i] = 0.f; accB[i] = 0.f; }
  __syncthreads();

  for (int icc = 0; icc < 4; ++icc) {
    if (icc) __syncthreads();
    for (int idx = tid; idx < 12 * 3 * 232; idx += 256) {
      int cl = idx / (3 * 232);
      int rem = idx - cl * (3 * 232);
      int rr = rem / 232, cc = rem - rr * 232;
      int c = icc * 12 + cl;
      int r1 = t - 1 + rr, w = cc - 1;
      float v = 0.f;
      if (r1 >= 0 && r1 < 512 && w >= 0 && w < 229) {
        const float* cw = c1w + c * 9;
        const float* m0 = melS + rr * 232 + cc - 1;
        float s = m0[0] * cw[0] + m0[1] * cw[1] + m0[2] * cw[2]
                + m0[232] * cw[3] + m0[233] * cw[4] + m0[234] * cw[5]
                + m0[464] * cw[6] + m0[465] * cw[7] + m0[466] * cw[8];
        s += c1b[c];
        float sc = bn1g[c] * rsqrtf(bn1v[c] + 1e-5f);
        v = fmaxf(s * sc + (bn1b[c] - bn1m[c] * sc), 0.f);
      }
      x1S[idx] = v;
    }
    for (int idx = tid; idx < 48 * 12 * 9; idx += 256) {
      int oc = idx / 108, rem = idx - oc * 108;
      wS[idx] = c2w[(oc * 48 + icc * 12) * 9 + rem];
    }
    __syncthreads();
    for (int i = 0; i < 22; ++i) {
      int oidx = tid + i * 256;
      if (oidx >= 5472) break;
      int oc = oidx / 114, wp = oidx - oc * 114;
      int w0 = 2 * wp;
      float a0 = accA[i], a1 = accB[i];
      const float* wp9 = wS + oc * 108;
      for (int icl = 0; icl < 12; ++icl) {
#pragma unroll
        for (int a = 0; a < 3; ++a) {
          const float* xr = x1S + (icl * 3 + a) * 232 + w0;
          float x0 = xr[0], x1 = xr[1], x2 = xr[2], x3 = xr[3];
          float wA = wp9[icl * 9 + a * 3 + 0];
          float wB = wp9[icl * 9 + a * 3 + 1];
          float wC = wp9[icl * 9 + a * 3 + 2];
          a0 = fmaf(x0, wA, a0); a0 = fmaf(x1, wB, a0); a0 = fmaf(x2, wC, a0);
          a1 = fmaf(x1, wA, a1); a1 = fmaf(x2, wB, a1); a1 = fmaf(x3, wC, a1);
        }
      }
      accA[i] = a0; accB[i] = a1;
    }
  }
  for (int i = 0; i < 22; ++i) {
    int oidx = tid + i * 256;
    if (oidx >= 5472) break;
    int oc = oidx / 114, wp = oidx - oc * 114;
    float sc = bn2g[oc] * rsqrtf(bn2v[oc] + 1e-5f);
    float sh = bn2b[oc] - bn2m[oc] * sc;
    float v0 = fmaxf((accA[i] + c2b[oc]) * sc + sh, 0.f);
    float v1 = fmaxf((accB[i] + c2b[oc]) * sc + sh, 0.f);
    A[((bl * 48 + oc) * 512 + t) * 114 + wp] = fmaxf(v0, v1);
  }
}

// ---------------------------------------------------------------------------
// K2: conv3+bn3+relu+pool(1,2). Grid = nb*510. Reads A_c (local), writes
// Bf_c GEMM-ready: Bf[(bl*510+t)][c*57+w].
// ---------------------------------------------------------------------------
__global__ __launch_bounds__(256) void conv3_kernel(
    const float* __restrict__ A,
    const float* __restrict__ c3w, const float* __restrict__ c3b,
    const float* __restrict__ bn3g, const float* __restrict__ bn3b,
    const float* __restrict__ bn3m, const float* __restrict__ bn3v,
    float* __restrict__ Bf)
{
  __shared__ float aS[16 * 3 * 116];
  __shared__ float wS[48 * 16 * 9];
  const int tid = threadIdx.x;
  const int bl = blockIdx.x / 510;
  const int t = blockIdx.x - bl * 510;

  for (int ocg = 0; ocg < 2; ++ocg) {
    float accA[11], accB[11];
#pragma unroll
    for (int i = 0; i < 11; ++i) { accA[i] = 0.f; accB[i] = 0.f; }
    for (int icc = 0; icc < 3; ++icc) {
      __syncthreads();
      for (int idx = tid; idx < 16 * 3 * 116; idx += 256) {
        int cl = idx / 348, rem = idx - cl * 348;
        int rr = rem / 116, cc = rem - rr * 116;
        int w = cc - 1;
        float v = 0.f;
        if (w >= 0 && w < 114) v = A[((bl * 48 + icc * 16 + cl) * 512 + t + rr) * 114 + w];
        aS[idx] = v;
      }
      for (int idx = tid; idx < 48 * 16 * 9; idx += 256) {
        int ocl = idx / 144, rem = idx - ocl * 144;
        wS[idx] = c3w[((ocg * 48 + ocl) * 48 + icc * 16) * 9 + rem];
      }
      __syncthreads();
      for (int i = 0; i < 11; ++i) {
        int oidx = tid + i * 256;
        if (oidx >= 2736) break;
        int ocl = oidx / 57, wp = oidx - ocl * 57;
        int w0 = 2 * wp;
        float a0 = accA[i], a1 = accB[i];
        const float* wb = wS + ocl * 144;
        for (int icl = 0; icl < 16; ++icl) {
#pragma unroll
          for (int a = 0; a < 3; ++a) {
            const float* xr = aS + (icl * 3 + a) * 116 + w0;
            float x0 = xr[0], x1 = xr[1], x2 = xr[2], x3 = xr[3];
            float wA = wb[icl * 9 + a * 3 + 0];
            float wB = wb[icl * 9 + a * 3 + 1];
            float wC = wb[icl * 9 + a * 3 + 2];
            a0 = fmaf(x0, wA, a0); a0 = fmaf(x1, wB, a0); a0 = fmaf(x2, wC, a0);
            a1 = fmaf(x1, wA, a1); a1 = fmaf(x2, wB, a1); a1 = fmaf(x3, wC, a1);
          }
        }
        accA[i] = a0; accB[i] = a1;
      }
    }
    for (int i = 0; i < 11; ++i) {
      int oidx = tid + i * 256;
      if (oidx >= 2736) break;
      int ocl = oidx / 57, wp = oidx - ocl * 57;
      int oc = ocg * 48 + ocl;
      float sc = bn3g[oc] * rsqrtf(bn3v[oc] + 1e-5f);
      float sh = bn3b[oc] - bn3m[oc] * sc;
      float v0 = fmaxf((accA[i] + c3b[oc]) * sc + sh, 0.f);
      float v1 = fmaxf((accB[i] + c3b[oc]) * sc + sh, 0.f);
      Bf[(size_t)(bl * 510 + t) * 5472 + oc * 57 + wp] = fmaxf(v0, v1);
    }
  }
}

// ---------------------------------------------------------------------------
// K3/K4: fp32 NT GEMM  C[M,N] = A[M,K(lda)] * B[N,K(ldb)]^T + bias(+bias2)
// ---------------------------------------------------------------------------
__global__ __launch_bounds__(256) void gemm_nt(
    const float* __restrict__ Am, const float* __restrict__ Bm,
    const float* __restrict__ bias, const float* __restrict__ bias2,
    float* __restrict__ C,
    int M, int N, int K, int lda, int ldb, int ldc)
{
  __shared__ float As[64 * 33];
  __shared__ float Bs[64 * 33];
  const int tid = threadIdx.x;
  const int m0 = blockIdx.x * 64, n0 = blockIdx.y * 64;
  const int tx = tid & 15, ty = tid >> 4;
  const int kq = (tid & 7) * 4, rw = tid >> 3;
  float acc[4][4];
#pragma unroll
  for (int i = 0; i < 4; ++i)
#pragma unroll
    for (int j = 0; j < 4; ++j) acc[i][j] = 0.f;

  for (int k0 = 0; k0 < K; k0 += 32) {
    int m1 = m0 + rw, m2 = m1 + 32;
    float4 va = make_float4(0.f, 0.f, 0.f, 0.f), vb = va;
    if (m1 < M) va = *(const float4*)(Am + (size_t)m1 * lda + k0 + kq);
    if (m2 < M) vb = *(const float4*)(Am + (size_t)m2 * lda + k0 + kq);
    float4 wa = *(const float4*)(Bm + (size_t)(n0 + rw) * ldb + k0 + kq);
    float4 wb = *(const float4*)(Bm + (size_t)(n0 + rw + 32) * ldb + k0 + kq);
    As[rw * 33 + kq + 0] = va.x; As[rw * 33 + kq + 1] = va.y;
    As[rw * 33 + kq + 2] = va.z; As[rw * 33 + kq + 3] = va.w;
    As[(rw + 32) * 33 + kq + 0] = vb.x; As[(rw + 32) * 33 + kq + 1] = vb.y;
    As[(rw + 32) * 33 + kq + 2] = vb.z; As[(rw + 32) * 33 + kq + 3] = vb.w;
    Bs[rw * 33 + kq + 0] = wa.x; Bs[rw * 33 + kq + 1] = wa.y;
    Bs[rw * 33 + kq + 2] = wa.z; Bs[rw * 33 + kq + 3] = wa.w;
    Bs[(rw + 32) * 33 + kq + 0] = wb.x; Bs[(rw + 32) * 33 + kq + 1] = wb.y;
    Bs[(rw + 32) * 33 + kq + 2] = wb.z; Bs[(rw + 32) * 33 + kq + 3] = wb.w;
    __syncthreads();
#pragma unroll 8
    for (int k = 0; k < 32; ++k) {
      float av[4], bv[4];
#pragma unroll
      for (int i = 0; i < 4; ++i) av[i] = As[(ty * 4 + i) * 33 + k];
#pragma unroll
      for (int j = 0; j < 4; ++j) bv[j] = Bs[(tx * 4 + j) * 33 + k];
#pragma unroll
      for (int i = 0; i < 4; ++i)
#pragma unroll
        for (int j = 0; j < 4; ++j) acc[i][j] = fmaf(av[i], bv[j], acc[i][j]);
    }
    __syncthreads();
  }
#pragma unroll
  for (int i = 0; i < 4; ++i) {
    int m = m0 + ty * 4 + i;
    if (m >= M) continue;
#pragma unroll
    for (int j = 0; j < 4; ++j) {
      int n = n0 + tx * 4 + j;
      float bz = bias[n] + (bias2 ? bias2[n] : 0.f);
      C[(size_t)m * ldc + n] = acc[i][j] + bz;
    }
  }
}

// ---------------------------------------------------------------------------
__global__ void init_state(float* __restrict__ h1g, float* __restrict__ h2g,
                           unsigned* __restrict__ bar) {
  int gid = blockIdx.x * 256 + threadIdx.x;
  if (gid < 24576) { h1g[gid] = 0.f; h2g[gid] = 0.f; }
  if (gid == 0) bar[0] = 0u;
}

// ---------------------------------------------------------------------------
// K6: persistent 2-layer LSTM + projection + argmax feedback.
// 192 blocks x 256 threads, cooperative launch. Block owns 4 units x 4 gates
// x 16 batches. useZ=1: layer-1 input GEMM precomputed in Z1a. useZ=0:
// compute input dot from aco (768 MACs) inline.
// ---------------------------------------------------------------------------
__global__ __launch_bounds__(256) void lstm_kernel(
    const float* __restrict__ Z1a,   // [8160][3072] (+biases) if useZ
    const float* __restrict__ whh0,  // [3072][768]
    const float* __restrict__ wih0,  // [3072][944]
    const float* __restrict__ wih1,  // [3072][768]
    const float* __restrict__ whh1,  // [3072][768]
    const float* __restrict__ bih1, const float* __restrict__ bhh1,
    const float* __restrict__ pw,    // [440][768]
    const float* __restrict__ pb,
    const float* __restrict__ emb,   // [5][2]
    float* __restrict__ h1g,         // [2][16*768]
    float* __restrict__ h2g,
    unsigned* __restrict__ bar,
    float* __restrict__ out,         // [16][510][88][5]
    int useZ,
    const float* __restrict__ aco,   // [8160][768] (used when !useZ)
    const float* __restrict__ bih0, const float* __restrict__ bhh0)
{
  __shared__ float hs[16 * 772];
  __shared__ float prevs[16 * 180];
  __shared__ float zl[256];
  const int tid = threadIdx.x;
  const int b = tid & 15, rr = tid >> 4;
  const int g = rr >> 2, ul = rr & 3;
  const int uB = blockIdx.x * 4;
  const int u = uB + ul, j = g * 768 + u;
  const float* w0r = whh0 + (size_t)j * 768;
  const float* w0x = wih0 + (size_t)j * 944;        // input part (!useZ)
  const float* wpr = w0x + 768;                      // prev part
  const float* w1r = wih1 + (size_t)j * 768;
  const float* w2r = whh1 + (size_t)j * 768;
  const float bL2 = bih1[j] + bhh1[j];
  const float bL1 = useZ ? 0.f : (bih0[j] + bhh0[j]);
  float c1r = 0.f, c2r = 0.f;
  unsigned nb = 0;
  const unsigned NG = gridDim.x;

  for (int t = 0; t < 510; ++t) {
    const int wb = t & 1, rb = wb ^ 1;
    // ---------------- PH1: layer-1 cell ----------------
    for (int idx = tid * 4; idx < 12288; idx += 1024) {
      float4 v = *(const float4*)(h1g + rb * 12288 + idx);
      int bb = idx / 768, kk = idx - bb * 768;
      *(float4*)(hs + bb * 772 + kk) = v;
    }
    if (t == 0) {
      for (int idx = tid; idx < 16 * 180; idx += 256) prevs[idx] = 0.f;
    } else {
      for (int idx = tid; idx < 16 * 88; idx += 256) {
        int bb = idx / 88, p = idx - bb * 88;
        const float* lg = out + ((size_t)(bb * 510 + (t - 1)) * 88 + p) * 5;
        float best = lg[0]; int bi = 0;
#pragma unroll
        for (int c = 1; c < 5; ++c) { float v = lg[c]; if (v > best) { best = v; bi = c; } }
        prevs[bb * 180 + 2 * p]     = emb[bi * 2];
        prevs[bb * 180 + 2 * p + 1] = emb[bi * 2 + 1];
      }
    }
    __syncthreads();
    {
      float acc;
      if (useZ) {
        acc = Z1a[(size_t)(b * 510 + t) * 3072 + j];
      } else {
        acc = bL1;
        const float* xr = aco + (size_t)(b * 510 + t) * 768;
#pragma unroll 8
        for (int k = 0; k < 768; k += 4) {
          float4 w4 = *(const float4*)(w0x + k);
          float4 x4 = *(const float4*)(xr + k);
          acc = fmaf(w4.x, x4.x, acc); acc = fmaf(w4.y, x4.y, acc);
          acc = fmaf(w4.z, x4.z, acc); acc = fmaf(w4.w, x4.w, acc);
        }
      }
      const float* hp = hs + b * 772;
#pragma unroll 8
      for (int k = 0; k < 768; k += 4) {
        float4 w4 = *(const float4*)(w0r + k);
        float4 h4 = *(const float4*)(hp + k);
        acc = fmaf(w4.x, h4.x, acc); acc = fmaf(w4.y, h4.y, acc);
        acc = fmaf(w4.z, h4.z, acc); acc = fmaf(w4.w, h4.w, acc);
      }
      const float* pp = prevs + b * 180;
#pragma unroll 4
      for (int k = 0; k < 176; k += 4) {
        float4 w4 = *(const float4*)(wpr + k);
        float4 p4 = *(const float4*)(pp + k);
        acc = fmaf(w4.x, p4.x, acc); acc = fmaf(w4.y, p4.y, acc);
        acc = fmaf(w4.z, p4.z, acc); acc = fmaf(w4.w, p4.w, acc);
      }
      zl[tid] = acc;
    }
    __syncthreads();
    if (tid < 64) {
      float zi = zl[tid], zf = zl[tid + 64], zg = zl[tid + 128], zo = zl[tid + 192];
      c1r = sigf(zf) * c1r + sigf(zi) * tanhf(zg);
      float hh = sigf(zo) * tanhf(c1r);
      h1g[wb * 12288 + (tid & 15) * 768 + uB + (tid >> 4)] = hh;
    }
    ++nb; gbar(bar, nb * NG);
    // ---------------- PH2: layer-2 cell ----------------
    for (int idx = tid * 4; idx < 12288; idx += 1024) {
      float4 v = *(const float4*)(h1g + wb * 12288 + idx);
      int bb = idx / 768, kk = idx - bb * 768;
      *(float4*)(hs + bb * 772 + kk) = v;
    }
    __syncthreads();
    float acc2 = bL2;
    {
      const float* hp = hs + b * 772;
#pragma unroll 8
      for (int k = 0; k < 768; k += 4) {
        float4 w4 = *(const float4*)(w1r + k);
        float4 h4 = *(const float4*)(hp + k);
        acc2 = fmaf(w4.x, h4.x, acc2); acc2 = fmaf(w4.y, h4.y, acc2);
        acc2 = fmaf(w4.z, h4.z, acc2); acc2 = fmaf(w4.w, h4.w, acc2);
      }
    }
    __syncthreads();
    for (int idx = tid * 4; idx < 12288; idx += 1024) {
      float4 v = *(const float4*)(h2g + rb * 12288 + idx);
      int bb = idx / 768, kk = idx - bb * 768;
      *(float4*)(hs + bb * 772 + kk) = v;
    }
    __syncthreads();
    {
      const float* hp = hs + b * 772;
#pragma unroll 8
      for (int k = 0; k < 768; k += 4) {
        float4 w4 = *(const float4*)(w2r + k);
        float4 h4 = *(const float4*)(hp + k);
        acc2 = fmaf(w4.x, h4.x, acc2); acc2 = fmaf(w4.y, h4.y, acc2);
        acc2 = fmaf(w4.z, h4.z, acc2); acc2 = fmaf(w4.w, h4.w, acc2);
      }
      zl[tid] = acc2;
    }
    __syncthreads();
    if (tid < 64) {
      float zi = zl[tid], zf = zl[tid + 64], zg = zl[tid + 128], zo = zl[tid + 192];
      c2r = sigf(zf) * c2r + sigf(zi) * tanhf(zg);
      float hh = sigf(zo) * tanhf(c2r);
      h2g[wb * 12288 + (tid & 15) * 768 + uB + (tid >> 4)] = hh;
    }
    ++nb; gbar(bar, nb * NG);
    // ---------------- PH3: projection ----------------
    {
      int gid = blockIdx.x * 256 + tid;
      if (gid < 7040) {
        int bb = gid / 440, n = gid - bb * 440;
        const float* hp = h2g + wb * 12288 + bb * 768;
        const float* wr = pw + (size_t)n * 768;
        float a = pb[n];
#pragma unroll 8
        for (int k = 0; k < 768; k += 4) {
          float4 w4 = *(const float4*)(wr + k);
          float4 h4 = *(const float4*)(hp + k);
          a = fmaf(w4.x, h4.x, a); a = fmaf(w4.y, h4.y, a);
          a = fmaf(w4.z, h4.z, a); a = fmaf(w4.w, h4.w, a);
        }
        out[(size_t)(bb * 510 + t) * 440 + n] = a;
      }
    }
    ++nb; gbar(bar, nb * NG);
  }
}

// ---------------------------------------------------------------------------
extern "C" void kernel_launch(void* const* d_in, const int* in_sizes, int n_in,
                              void* d_out, int out_size, void* d_ws, size_t ws_size,
                              hipStream_t stream) {
  (void)in_sizes; (void)n_in; (void)out_size;
  const float* mel  = (const float*)d_in[0];
  const float* c1w  = (const float*)d_in[1];
  const float* c1b  = (const float*)d_in[2];
  const float* c2w  = (const float*)d_in[3];
  const float* c2b  = (const float*)d_in[4];
  const float* c3w  = (const float*)d_in[5];
  const float* c3b  = (const float*)d_in[6];
  const float* bn1g = (const float*)d_in[7];
  const float* bn1b = (const float*)d_in[8];
  const float* bn1m = (const float*)d_in[9];
  const float* bn1v = (const float*)d_in[10];
  const float* bn2g = (const float*)d_in[11];
  const float* bn2b = (const float*)d_in[12];
  const float* bn2m = (const float*)d_in[13];
  const float* bn2v = (const float*)d_in[14];
  const float* bn3g = (const float*)d_in[15];
  const float* bn3b = (const float*)d_in[16];
  const float* bn3m = (const float*)d_in[17];
  const float* bn3v = (const float*)d_in[18];
  const float* fcw  = (const float*)d_in[19];
  const float* fcb  = (const float*)d_in[20];
  const float* wih0 = (const float*)d_in[21];
  const float* whh0 = (const float*)d_in[22];
  const float* bih0 = (const float*)d_in[23];
  const float* bhh0 = (const float*)d_in[24];
  const float* wih1 = (const float*)d_in[25];
  const float* whh1 = (const float*)d_in[26];
  const float* bih1 = (const float*)d_in[27];
  const float* bhh1 = (const float*)d_in[28];
  const float* pw   = (const float*)d_in[29];
  const float* pb   = (const float*)d_in[30];
  const float* emb  = (const float*)d_in[31];

  float* ws  = (float*)d_ws;
  float* outp = (float*)d_out;

  // Path selection on ws_size (constant across calls -> graph-safe).
  const size_t needA = (ACO_FL + Z1A_FL + ST_FL) * 4ull;  // ~125.5 MB
  int useZ = (ws_size >= needA) ? 1 : 0;
  const int CB = useZ ? 4 : 1;          // batches per conv chunk
  const int nchunks = 16 / CB;
  const size_t A_FL  = (size_t)CB * 48 * 512 * 114;
  const size_t BF_FL = (size_t)CB * 510 * 5472;

  float* aco = ws;                                   // [8160][768]
  float* z1a = ws + ACO_FL;                          // [8160][3072] (path A)
  float* Ac  = useZ ? (ws + ACO_FL) : (ws + ACO_FL); // conv scratch (aliases z1a in A)
  float* Bfc = Ac + A_FL;
  float* st  = useZ ? (ws + ACO_FL + Z1A_FL) : (Bfc + BF_FL);
  float* h1g = st;
  float* h2g = st + 24576;
  unsigned* bar = (unsigned*)(st + 49152);

  for (int ch = 0; ch < nchunks; ++ch) {
    int b0 = ch * CB;
    hipLaunchKernelGGL(conv12_kernel, dim3(CB * 512), dim3(256), 0, stream,
                       mel, c1w, c1b, bn1g, bn1b, bn1m, bn1v,
                       c2w, c2b, bn2g, bn2b, bn2m, bn2v, Ac, b0);
    hipLaunchKernelGGL(conv3_kernel, dim3(CB * 510), dim3(256), 0, stream,
                       Ac, c3w, c3b, bn3g, bn3b, bn3m, bn3v, Bfc);
    int M = CB * 510;
    hipLaunchKernelGGL(gemm_nt, dim3((M + 63) / 64, 12), dim3(256), 0, stream,
                       Bfc, fcw, fcb, (const float*)nullptr,
                       aco + (size_t)b0 * 510 * 768,
                       M, 768, 5472, 5472, 5472, 768);
  }
  if (useZ) {
    hipLaunchKernelGGL(gemm_nt, dim3(128, 48), dim3(256), 0, stream,
                       aco, wih0, bih0, bhh0, z1a,
                       8160, 3072, 768, 768, 944, 3072);
  }
  hipLaunchKernelGGL(init_state, dim3(96), dim3(256), 0, stream, h1g, h2g, bar);

  // LSTM: cooperative launch (guaranteed co-residency); fall back to a plain
  // launch if the runtime rejects it (192 blocks < 256 CUs co-resident anyway).
  {
    const float* z1a_c = z1a;
    const float* aco_c = aco;
    void* args[] = {
      (void*)&z1a_c, (void*)&whh0, (void*)&wih0, (void*)&wih1, (void*)&whh1,
      (void*)&bih1, (void*)&bhh1, (void*)&pw, (void*)&pb, (void*)&emb,
      (void*)&h1g, (void*)&h2g, (void*)&bar, (void*)&outp, (void*)&useZ,
      (void*)&aco_c, (void*)&bih0, (void*)&bhh0
    };
    hipError_t e = hipLaunchCooperativeKernel((const void*)lstm_kernel,
                                              dim3(192), dim3(256), args, 0, stream);
    if (e != hipSuccess) {
      (void)hipGetLastError();
      hipLaunchKernelGGL(lstm_kernel, dim3(192), dim3(256), 0, stream,
                         z1a_c, whh0, wih0, wih1, whh1, bih1, bhh1,
                         pw, pb, emb, h1g, h2g, bar, outp, useZ,
                         aco_c, bih0, bhh0);
    }
  }
}

// Round 3
// 58342.395 us; speedup vs baseline: 1.9331x; 1.9331x over previous
//
#include <hip/hip_runtime.h>
#include <math.h>

// ============================================================================
// AR_Transcriber round 3.
// Fix: round-2 LSTM was latency-bound (VALUBusy 2.1%, 10 GB refetch/step) --
// the agent-scope __threadfence() in the grid barrier invalidated all of L2
// every step, evicting the 28 MB weight working set 1530 times.
// Now: NO fences. Cross-block state (h1/h2/prev-embeddings) moves through
// relaxed agent-scope atomics (L2-bypassing, coherent at L3); weights stay
// L2-resident. Argmax feedback computed by projection blocks, published as
// packed embedding pairs (prevg). Z1a stored transposed [t][j][b] for
// coalesced per-step reads. Dots use 4 accumulators.
// ============================================================================

typedef unsigned long long ull;

#define ACO_FL   6266880ull   // 8160*768
#define Z1A_FL  25067520ull   // 8160*3072

__device__ __forceinline__ float sigf(float x) { return 1.0f / (1.0f + expf(-x)); }

__device__ __forceinline__ ull pack2(float x, float y) {
  union { float f[2]; ull u; } c; c.f[0] = x; c.f[1] = y; return c.u;
}
__device__ __forceinline__ float2 unpack2(ull u) {
  union { ull u; float2 v; } c; c.u = u; return c.v;
}
__device__ __forceinline__ ull at_load(const ull* p) {
  return __hip_atomic_load((ull*)p, __ATOMIC_RELAXED, __HIP_MEMORY_SCOPE_AGENT);
}
__device__ __forceinline__ void at_store(ull* p, ull v) {
  __hip_atomic_store(p, v, __ATOMIC_RELAXED, __HIP_MEMORY_SCOPE_AGENT);
}

// Fence-free grid barrier: __syncthreads() drains each wave's vmem before
// thread 0 arrives; counter RMW + polls are relaxed agent-scope atomics
// (performed at the coherence point -> no L2 maintenance).
__device__ __forceinline__ void gbar(unsigned* cnt, unsigned target) {
  __syncthreads();
  if (threadIdx.x == 0) {
    __builtin_amdgcn_s_waitcnt(0);
    __atomic_signal_fence(__ATOMIC_SEQ_CST);
    __hip_atomic_fetch_add(cnt, 1u, __ATOMIC_RELAXED, __HIP_MEMORY_SCOPE_AGENT);
    while (__hip_atomic_load(cnt, __ATOMIC_RELAXED, __HIP_MEMORY_SCOPE_AGENT) < target) {
      __builtin_amdgcn_s_sleep(2);
    }
    __atomic_signal_fence(__ATOMIC_SEQ_CST);
  }
  __syncthreads();
}

// 16 FMAs into 4 accumulators (a0..a3 must be in scope)
#define DOT16(WPTR, HPTR, K)                                                  \
  {                                                                           \
    float4 w0_ = *(const float4*)((WPTR) + (K));                              \
    float4 h0_ = *(const float4*)((HPTR) + (K));                              \
    float4 w1_ = *(const float4*)((WPTR) + (K) + 4);                          \
    float4 h1_ = *(const float4*)((HPTR) + (K) + 4);                          \
    float4 w2_ = *(const float4*)((WPTR) + (K) + 8);                          \
    float4 h2_ = *(const float4*)((HPTR) + (K) + 8);                          \
    float4 w3_ = *(const float4*)((WPTR) + (K) + 12);                         \
    float4 h3_ = *(const float4*)((HPTR) + (K) + 12);                         \
    a0 = fmaf(w0_.x, h0_.x, a0); a0 = fmaf(w0_.y, h0_.y, a0);                 \
    a0 = fmaf(w0_.z, h0_.z, a0); a0 = fmaf(w0_.w, h0_.w, a0);                 \
    a1 = fmaf(w1_.x, h1_.x, a1); a1 = fmaf(w1_.y, h1_.y, a1);                 \
    a1 = fmaf(w1_.z, h1_.z, a1); a1 = fmaf(w1_.w, h1_.w, a1);                 \
    a2 = fmaf(w2_.x, h2_.x, a2); a2 = fmaf(w2_.y, h2_.y, a2);                 \
    a2 = fmaf(w2_.z, h2_.z, a2); a2 = fmaf(w2_.w, h2_.w, a2);                 \
    a3 = fmaf(w3_.x, h3_.x, a3); a3 = fmaf(w3_.y, h3_.y, a3);                 \
    a3 = fmaf(w3_.z, h3_.z, a3); a3 = fmaf(w3_.w, h3_.w, a3);                 \
  }

// ---------------------------------------------------------------------------
// K1: fused conv1+bn1+relu -> conv2+bn2+relu -> pool(1,2).
// ---------------------------------------------------------------------------
__global__ __launch_bounds__(256) void conv12_kernel(
    const float* __restrict__ mel,
    const float* __restrict__ c1w, const float* __restrict__ c1b,
    const float* __restrict__ bn1g, const float* __restrict__ bn1b,
    const float* __restrict__ bn1m, const float* __restrict__ bn1v,
    const float* __restrict__ c2w, const float* __restrict__ c2b,
    const float* __restrict__ bn2g, const float* __restrict__ bn2b,
    const float* __restrict__ bn2m, const float* __restrict__ bn2v,
    float* __restrict__ A, int b0)
{
  __shared__ float melS[5 * 232];
  __shared__ float x1S[12 * 3 * 232];
  __shared__ float wS[48 * 12 * 9];
  const int tid = threadIdx.x;
  const int bl = blockIdx.x >> 9;
  const int b = b0 + bl;
  const int t = blockIdx.x & 511;

  for (int idx = tid; idx < 5 * 232; idx += 256) {
    int rr = idx / 232, cc = idx - rr * 232;
    int r = t - 2 + rr, w = cc - 1;
    float v = 0.f;
    if (r >= 0 && r < 512 && w >= 0 && w < 229) v = mel[(b * 512 + r) * 229 + w];
    melS[idx] = v;
  }

  float accA[22], accB[22];
#pragma unroll
  for (int i = 0; i < 22; ++i) { accA[i] = 0.f; accB[i] = 0.f; }
  __syncthreads();

  for (int icc = 0; icc < 4; ++icc) {
    if (icc) __syncthreads();
    for (int idx = tid; idx < 12 * 3 * 232; idx += 256) {
      int cl = idx / (3 * 232);
      int rem = idx - cl * (3 * 232);
      int rr = rem / 232, cc = rem - rr * 232;
      int c = icc * 12 + cl;
      int r1 = t - 1 + rr, w = cc - 1;
      float v = 0.f;
      if (r1 >= 0 && r1 < 512 && w >= 0 && w < 229) {
        const float* cw = c1w + c * 9;
        const float* m0 = melS + rr * 232 + cc - 1;
        float s = m0[0] * cw[0] + m0[1] * cw[1] + m0[2] * cw[2]
                + m0[232] * cw[3] + m0[233] * cw[4] + m0[234] * cw[5]
                + m0[464] * cw[6] + m0[465] * cw[7] + m0[466] * cw[8];
        s += c1b[c];
        float sc = bn1g[c] * rsqrtf(bn1v[c] + 1e-5f);
        v = fmaxf(s * sc + (bn1b[c] - bn1m[c] * sc), 0.f);
      }
      x1S[idx] = v;
    }
    for (int idx = tid; idx < 48 * 12 * 9; idx += 256) {
      int oc = idx / 108, rem = idx - oc * 108;
      wS[idx] = c2w[(oc * 48 + icc * 12) * 9 + rem];
    }
    __syncthreads();
    for (int i = 0; i < 22; ++i) {
      int oidx = tid + i * 256;
      if (oidx >= 5472) break;
      int oc = oidx / 114, wp = oidx - oc * 114;
      int w0 = 2 * wp;
      float a0 = accA[i], a1 = accB[i];
      const float* wp9 = wS + oc * 108;
      for (int icl = 0; icl < 12; ++icl) {
#pragma unroll
        for (int a = 0; a < 3; ++a) {
          const float* xr = x1S + (icl * 3 + a) * 232 + w0;
          float x0 = xr[0], x1 = xr[1], x2 = xr[2], x3 = xr[3];
          float wA = wp9[icl * 9 + a * 3 + 0];
          float wB = wp9[icl * 9 + a * 3 + 1];
          float wC = wp9[icl * 9 + a * 3 + 2];
          a0 = fmaf(x0, wA, a0); a0 = fmaf(x1, wB, a0); a0 = fmaf(x2, wC, a0);
          a1 = fmaf(x1, wA, a1); a1 = fmaf(x2, wB, a1); a1 = fmaf(x3, wC, a1);
        }
      }
      accA[i] = a0; accB[i] = a1;
    }
  }
  for (int i = 0; i < 22; ++i) {
    int oidx = tid + i * 256;
    if (oidx >= 5472) break;
    int oc = oidx / 114, wp = oidx - oc * 114;
    float sc = bn2g[oc] * rsqrtf(bn2v[oc] + 1e-5f);
    float sh = bn2b[oc] - bn2m[oc] * sc;
    float v0 = fmaxf((accA[i] + c2b[oc]) * sc + sh, 0.f);
    float v1 = fmaxf((accB[i] + c2b[oc]) * sc + sh, 0.f);
    A[((bl * 48 + oc) * 512 + t) * 114 + wp] = fmaxf(v0, v1);
  }
}

// ---------------------------------------------------------------------------
// K2: conv3+bn3+relu+pool(1,2); GEMM-ready output.
// ---------------------------------------------------------------------------
__global__ __launch_bounds__(256) void conv3_kernel(
    const float* __restrict__ A,
    const float* __restrict__ c3w, const float* __restrict__ c3b,
    const float* __restrict__ bn3g, const float* __restrict__ bn3b,
    const float* __restrict__ bn3m, const float* __restrict__ bn3v,
    float* __restrict__ Bf)
{
  __shared__ float aS[16 * 3 * 116];
  __shared__ float wS[48 * 16 * 9];
  const int tid = threadIdx.x;
  const int bl = blockIdx.x / 510;
  const int t = blockIdx.x - bl * 510;

  for (int ocg = 0; ocg < 2; ++ocg) {
    float accA[11], accB[11];
#pragma unroll
    for (int i = 0; i < 11; ++i) { accA[i] = 0.f; accB[i] = 0.f; }
    for (int icc = 0; icc < 3; ++icc) {
      __syncthreads();
      for (int idx = tid; idx < 16 * 3 * 116; idx += 256) {
        int cl = idx / 348, rem = idx - cl * 348;
        int rr = rem / 116, cc = rem - rr * 116;
        int w = cc - 1;
        float v = 0.f;
        if (w >= 0 && w < 114) v = A[((bl * 48 + icc * 16 + cl) * 512 + t + rr) * 114 + w];
        aS[idx] = v;
      }
      for (int idx = tid; idx < 48 * 16 * 9; idx += 256) {
        int ocl = idx / 144, rem = idx - ocl * 144;
        wS[idx] = c3w[((ocg * 48 + ocl) * 48 + icc * 16) * 9 + rem];
      }
      __syncthreads();
      for (int i = 0; i < 11; ++i) {
        int oidx = tid + i * 256;
        if (oidx >= 2736) break;
        int ocl = oidx / 57, wp = oidx - ocl * 57;
        int w0 = 2 * wp;
        float a0 = accA[i], a1 = accB[i];
        const float* wb = wS + ocl * 144;
        for (int icl = 0; icl < 16; ++icl) {
#pragma unroll
          for (int a = 0; a < 3; ++a) {
            const float* xr = aS + (icl * 3 + a) * 116 + w0;
            float x0 = xr[0], x1 = xr[1], x2 = xr[2], x3 = xr[3];
            float wA = wb[icl * 9 + a * 3 + 0];
            float wB = wb[icl * 9 + a * 3 + 1];
            float wC = wb[icl * 9 + a * 3 + 2];
            a0 = fmaf(x0, wA, a0); a0 = fmaf(x1, wB, a0); a0 = fmaf(x2, wC, a0);
            a1 = fmaf(x1, wA, a1); a1 = fmaf(x2, wB, a1); a1 = fmaf(x3, wC, a1);
          }
        }
        accA[i] = a0; accB[i] = a1;
      }
    }
    for (int i = 0; i < 11; ++i) {
      int oidx = tid + i * 256;
      if (oidx >= 2736) break;
      int ocl = oidx / 57, wp = oidx - ocl * 57;
      int oc = ocg * 48 + ocl;
      float sc = bn3g[oc] * rsqrtf(bn3v[oc] + 1e-5f);
      float sh = bn3b[oc] - bn3m[oc] * sc;
      float v0 = fmaxf((accA[i] + c3b[oc]) * sc + sh, 0.f);
      float v1 = fmaxf((accB[i] + c3b[oc]) * sc + sh, 0.f);
      Bf[(size_t)(bl * 510 + t) * 5472 + oc * 57 + wp] = fmaxf(v0, v1);
    }
  }
}

// ---------------------------------------------------------------------------
// K3/K4: fp32 NT GEMM. zt=1 stores transposed-for-LSTM: C[((t*3072)+n)*16+b]
// where m = b*510+t.
// ---------------------------------------------------------------------------
__global__ __launch_bounds__(256) void gemm_nt(
    const float* __restrict__ Am, const float* __restrict__ Bm,
    const float* __restrict__ bias, const float* __restrict__ bias2,
    float* __restrict__ C,
    int M, int N, int K, int lda, int ldb, int ldc, int zt)
{
  __shared__ float As[64 * 33];
  __shared__ float Bs[64 * 33];
  const int tid = threadIdx.x;
  const int m0 = blockIdx.x * 64, n0 = blockIdx.y * 64;
  const int tx = tid & 15, ty = tid >> 4;
  const int kq = (tid & 7) * 4, rw = tid >> 3;
  float acc[4][4];
#pragma unroll
  for (int i = 0; i < 4; ++i)
#pragma unroll
    for (int j = 0; j < 4; ++j) acc[i][j] = 0.f;

  for (int k0 = 0; k0 < K; k0 += 32) {
    int m1 = m0 + rw, m2 = m1 + 32;
    float4 va = make_float4(0.f, 0.f, 0.f, 0.f), vb = va;
    if (m1 < M) va = *(const float4*)(Am + (size_t)m1 * lda + k0 + kq);
    if (m2 < M) vb = *(const float4*)(Am + (size_t)m2 * lda + k0 + kq);
    float4 wa = *(const float4*)(Bm + (size_t)(n0 + rw) * ldb + k0 + kq);
    float4 wb = *(const float4*)(Bm + (size_t)(n0 + rw + 32) * ldb + k0 + kq);
    As[rw * 33 + kq + 0] = va.x; As[rw * 33 + kq + 1] = va.y;
    As[rw * 33 + kq + 2] = va.z; As[rw * 33 + kq + 3] = va.w;
    As[(rw + 32) * 33 + kq + 0] = vb.x; As[(rw + 32) * 33 + kq + 1] = vb.y;
    As[(rw + 32) * 33 + kq + 2] = vb.z; As[(rw + 32) * 33 + kq + 3] = vb.w;
    Bs[rw * 33 + kq + 0] = wa.x; Bs[rw * 33 + kq + 1] = wa.y;
    Bs[rw * 33 + kq + 2] = wa.z; Bs[rw * 33 + kq + 3] = wa.w;
    Bs[(rw + 32) * 33 + kq + 0] = wb.x; Bs[(rw + 32) * 33 + kq + 1] = wb.y;
    Bs[(rw + 32) * 33 + kq + 2] = wb.z; Bs[(rw + 32) * 33 + kq + 3] = wb.w;
    __syncthreads();
#pragma unroll 8
    for (int k = 0; k < 32; ++k) {
      float av[4], bv[4];
#pragma unroll
      for (int i = 0; i < 4; ++i) av[i] = As[(ty * 4 + i) * 33 + k];
#pragma unroll
      for (int j = 0; j < 4; ++j) bv[j] = Bs[(tx * 4 + j) * 33 + k];
#pragma unroll
      for (int i = 0; i < 4; ++i)
#pragma unroll
        for (int j = 0; j < 4; ++j) acc[i][j] = fmaf(av[i], bv[j], acc[i][j]);
    }
    __syncthreads();
  }
#pragma unroll
  for (int i = 0; i < 4; ++i) {
    int m = m0 + ty * 4 + i;
    if (m >= M) continue;
#pragma unroll
    for (int j = 0; j < 4; ++j) {
      int n = n0 + tx * 4 + j;
      float bz = bias[n] + (bias2 ? bias2[n] : 0.f);
      if (zt) {
        int bb = m / 510, tt = m - bb * 510;
        C[((size_t)tt * 3072 + n) * 16 + bb] = acc[i][j] + bz;
      } else {
        C[(size_t)m * ldc + n] = acc[i][j] + bz;
      }
    }
  }
}

// ---------------------------------------------------------------------------
// K5: zero LSTM state (atomic stores so sc-bypassing readers see them).
// ---------------------------------------------------------------------------
__global__ void init_state(ull* __restrict__ h1g, ull* __restrict__ h2g,
                           unsigned* __restrict__ bar) {
  int gid = blockIdx.x * 256 + threadIdx.x;
  if (gid < 12288) { at_store(h1g + gid, 0ull); at_store(h2g + gid, 0ull); }
  if (gid == 0) __hip_atomic_store(bar, 0u, __ATOMIC_RELAXED, __HIP_MEMORY_SCOPE_AGENT);
}

// ---------------------------------------------------------------------------
// K6: persistent 2-layer LSTM + projection + argmax feedback.
// 192 blocks x 256 threads (cooperative). Block owns 4 hidden units.
// h state: packed float2 in ull, double-buffered, exchanged via relaxed
// agent atomics. prevg: packed embedding pairs [16][88].
// ---------------------------------------------------------------------------
__global__ __launch_bounds__(256) void lstm_kernel(
    const float* __restrict__ Z1aT,  // [510][3072][16] (t,j,b) if useZ
    const float* __restrict__ whh0,  // [3072][768]
    const float* __restrict__ wih0,  // [3072][944]
    const float* __restrict__ wih1,  // [3072][768]
    const float* __restrict__ whh1,  // [3072][768]
    const float* __restrict__ bih0, const float* __restrict__ bhh0,
    const float* __restrict__ bih1, const float* __restrict__ bhh1,
    const float* __restrict__ pw,    // [440][768]
    const float* __restrict__ pb,
    const float* __restrict__ emb,   // [5][2]
    ull* __restrict__ h1g,           // [2][16][384] packed
    ull* __restrict__ h2g,
    ull* __restrict__ prevg,         // [16][88] packed emb pairs
    unsigned* __restrict__ bar,
    float* __restrict__ out,         // [16][510][440]
    int useZ,
    const float* __restrict__ aco)   // [8160][768] (used when !useZ)
{
  __shared__ float hs[16 * 772];
  __shared__ float prevs[16 * 180];
  __shared__ float zl[256];
  const int tid = threadIdx.x;
  const int b = tid & 15, rr = tid >> 4;
  const int uB = blockIdx.x * 4;
  const int g = rr >> 2, ul = rr & 3;
  const int j = g * 768 + uB + ul;
  const float* w0r = whh0 + (size_t)j * 768;
  const float* w0x = wih0 + (size_t)j * 944;
  const float* wpr = w0x + 768;
  const float* w1r = wih1 + (size_t)j * 768;
  const float* w2r = whh1 + (size_t)j * 768;
  // cell-update thread constants (tid<32): b=tid&15, unit pair pr=tid>>4
  const int ub_ = tid & 15, pr_ = (tid >> 4) & 1;
  float bl1[4][2], bl2[4][2];
  float c1s[2] = {0.f, 0.f}, c2s[2] = {0.f, 0.f};
  if (tid < 32) {
#pragma unroll
    for (int gg = 0; gg < 4; ++gg)
#pragma unroll
      for (int q = 0; q < 2; ++q) {
        int jj = gg * 768 + uB + pr_ * 2 + q;
        bl1[gg][q] = useZ ? 0.f : (bih0[jj] + bhh0[jj]);
        bl2[gg][q] = bih1[jj] + bhh1[jj];
      }
  }
  unsigned nb = 0;
  const unsigned NG = gridDim.x;

  for (int t = 0; t < 510; ++t) {
    const int wbuf = t & 1, rbuf = wbuf ^ 1;
    float xa = 0.f;
    if (!useZ) {
      // stage x(t) rows, dot with wih0 input part
      for (int idx = tid * 4; idx < 12288; idx += 1024) {
        int bb = idx / 768, kk = idx - bb * 768;
        *(float4*)(hs + bb * 772 + kk) =
            *(const float4*)(aco + (size_t)(bb * 510 + t) * 768 + kk);
      }
      __syncthreads();
      {
        float a0 = 0.f, a1 = 0.f, a2 = 0.f, a3 = 0.f;
        const float* hp = hs + b * 772;
#pragma unroll 4
        for (int k = 0; k < 768; k += 16) DOT16(w0x, hp, k);
        xa = (a0 + a1) + (a2 + a3);
      }
      __syncthreads();
    }
    // ---- stage h1(t-1) + prev embeddings ----
    for (int idx = tid; idx < 6144; idx += 256) {
      float2 v = unpack2(at_load(h1g + rbuf * 6144 + idx));
      int bb = idx / 384, kk = (idx - bb * 384) * 2;
      *(float2*)(hs + bb * 772 + kk) = v;
    }
    if (t == 0) {
      for (int idx = tid; idx < 16 * 180; idx += 256) prevs[idx] = 0.f;
    } else {
      for (int idx = tid; idx < 1408; idx += 256) {
        int bb = idx / 88, p = idx - bb * 88;
        float2 e = unpack2(at_load(prevg + idx));
        *(float2*)(prevs + bb * 180 + 2 * p) = e;
      }
    }
    __syncthreads();
    // ---- PH1 dot: whh0 . h1(t-1) + wprev . prev ----
    {
      float a0 = 0.f, a1 = 0.f, a2 = 0.f, a3 = 0.f;
      const float* hp = hs + b * 772;
#pragma unroll 4
      for (int k = 0; k < 768; k += 16) DOT16(w0r, hp, k);
      const float* ppv = prevs + b * 180;
#pragma unroll 2
      for (int k = 0; k < 176; k += 8) {
        float4 w0_ = *(const float4*)(wpr + k);
        float4 p0_ = *(const float4*)(ppv + k);
        float4 w1_ = *(const float4*)(wpr + k + 4);
        float4 p1_ = *(const float4*)(ppv + k + 4);
        a0 = fmaf(w0_.x, p0_.x, a0); a0 = fmaf(w0_.y, p0_.y, a0);
        a0 = fmaf(w0_.z, p0_.z, a0); a0 = fmaf(w0_.w, p0_.w, a0);
        a1 = fmaf(w1_.x, p1_.x, a1); a1 = fmaf(w1_.y, p1_.y, a1);
        a1 = fmaf(w1_.z, p1_.z, a1); a1 = fmaf(w1_.w, p1_.w, a1);
      }
      zl[tid] = ((a0 + a1) + (a2 + a3)) + xa;
    }
    __syncthreads();
    // ---- PH1 cell update (tid<32; 2 units each) ----
    if (tid < 32) {
      float hv[2];
#pragma unroll
      for (int q = 0; q < 2; ++q) {
        int uloc = pr_ * 2 + q;
        int uu = uB + uloc;
        float zi = zl[ub_ + 16 * (0 + uloc)] + bl1[0][q];
        float zf = zl[ub_ + 16 * (4 + uloc)] + bl1[1][q];
        float zg = zl[ub_ + 16 * (8 + uloc)] + bl1[2][q];
        float zo = zl[ub_ + 16 * (12 + uloc)] + bl1[3][q];
        if (useZ) {
          const float* zt = Z1aT + (size_t)t * 3072 * 16;
          zi += zt[(size_t)(0 * 768 + uu) * 16 + ub_];
          zf += zt[(size_t)(1 * 768 + uu) * 16 + ub_];
          zg += zt[(size_t)(2 * 768 + uu) * 16 + ub_];
          zo += zt[(size_t)(3 * 768 + uu) * 16 + ub_];
        }
        c1s[q] = sigf(zf) * c1s[q] + sigf(zi) * tanhf(zg);
        hv[q] = sigf(zo) * tanhf(c1s[q]);
      }
      at_store(h1g + wbuf * 6144 + ub_ * 384 + blockIdx.x * 2 + pr_,
               pack2(hv[0], hv[1]));
    }
    ++nb; gbar(bar, nb * NG);
    // ---- PH2: stage h1(t), dot wih1 ----
    for (int idx = tid; idx < 6144; idx += 256) {
      float2 v = unpack2(at_load(h1g + wbuf * 6144 + idx));
      int bb = idx / 384, kk = (idx - bb * 384) * 2;
      *(float2*)(hs + bb * 772 + kk) = v;
    }
    __syncthreads();
    float s2a;
    {
      float a0 = 0.f, a1 = 0.f, a2 = 0.f, a3 = 0.f;
      const float* hp = hs + b * 772;
#pragma unroll 4
      for (int k = 0; k < 768; k += 16) DOT16(w1r, hp, k);
      s2a = (a0 + a1) + (a2 + a3);
    }
    __syncthreads();
    // ---- stage h2(t-1), dot whh1 ----
    for (int idx = tid; idx < 6144; idx += 256) {
      float2 v = unpack2(at_load(h2g + rbuf * 6144 + idx));
      int bb = idx / 384, kk = (idx - bb * 384) * 2;
      *(float2*)(hs + bb * 772 + kk) = v;
    }
    __syncthreads();
    {
      float a0 = 0.f, a1 = 0.f, a2 = 0.f, a3 = 0.f;
      const float* hp = hs + b * 772;
#pragma unroll 4
      for (int k = 0; k < 768; k += 16) DOT16(w2r, hp, k);
      zl[tid] = s2a + (a0 + a1) + (a2 + a3);
    }
    __syncthreads();
    // ---- PH2 cell update ----
    if (tid < 32) {
      float hv[2];
#pragma unroll
      for (int q = 0; q < 2; ++q) {
        int uloc = pr_ * 2 + q;
        float zi = zl[ub_ + 16 * (0 + uloc)] + bl2[0][q];
        float zf = zl[ub_ + 16 * (4 + uloc)] + bl2[1][q];
        float zg = zl[ub_ + 16 * (8 + uloc)] + bl2[2][q];
        float zo = zl[ub_ + 16 * (12 + uloc)] + bl2[3][q];
        c2s[q] = sigf(zf) * c2s[q] + sigf(zi) * tanhf(zg);
        hv[q] = sigf(zo) * tanhf(c2s[q]);
      }
      at_store(h2g + wbuf * 6144 + ub_ * 384 + blockIdx.x * 2 + pr_,
               pack2(hv[0], hv[1]));
    }
    ++nb; gbar(bar, nb * NG);
    // ---- PH3: projection + argmax (blocks 0..31: (batch, half)) ----
    if (blockIdx.x < 32) {
      const int bb = blockIdx.x >> 1;
      const int n0 = (blockIdx.x & 1) * 220;
      for (int idx = tid; idx < 384; idx += 256) {
        float2 v = unpack2(at_load(h2g + wbuf * 6144 + bb * 384 + idx));
        *(float2*)(hs + 2 * idx) = v;
      }
      __syncthreads();
      if (tid < 220) {
        const float* wr = pw + (size_t)(n0 + tid) * 768;
        float a0 = 0.f, a1 = 0.f, a2 = 0.f, a3 = 0.f;
        const float* hp = hs;
#pragma unroll 4
        for (int k = 0; k < 768; k += 16) DOT16(wr, hp, k);
        float lg = ((a0 + a1) + (a2 + a3)) + pb[n0 + tid];
        out[(size_t)(bb * 510 + t) * 440 + n0 + tid] = lg;
        zl[tid] = lg;
      }
      __syncthreads();
      if (tid < 44) {
        float best = zl[tid * 5]; int bi = 0;
#pragma unroll
        for (int c = 1; c < 5; ++c) {
          float v = zl[tid * 5 + c];
          if (v > best) { best = v; bi = c; }
        }
        at_store(prevg + bb * 88 + (n0 / 5) + tid,
                 pack2(emb[bi * 2], emb[bi * 2 + 1]));
      }
    }
    ++nb; gbar(bar, nb * NG);
  }
}

// ---------------------------------------------------------------------------
extern "C" void kernel_launch(void* const* d_in, const int* in_sizes, int n_in,
                              void* d_out, int out_size, void* d_ws, size_t ws_size,
                              hipStream_t stream) {
  (void)in_sizes; (void)n_in; (void)out_size;
  const float* mel  = (const float*)d_in[0];
  const float* c1w  = (const float*)d_in[1];
  const float* c1b  = (const float*)d_in[2];
  const float* c2w  = (const float*)d_in[3];
  const float* c2b  = (const float*)d_in[4];
  const float* c3w  = (const float*)d_in[5];
  const float* c3b  = (const float*)d_in[6];
  const float* bn1g = (const float*)d_in[7];
  const float* bn1b = (const float*)d_in[8];
  const float* bn1m = (const float*)d_in[9];
  const float* bn1v = (const float*)d_in[10];
  const float* bn2g = (const float*)d_in[11];
  const float* bn2b = (const float*)d_in[12];
  const float* bn2m = (const float*)d_in[13];
  const float* bn2v = (const float*)d_in[14];
  const float* bn3g = (const float*)d_in[15];
  const float* bn3b = (const float*)d_in[16];
  const float* bn3m = (const float*)d_in[17];
  const float* bn3v = (const float*)d_in[18];
  const float* fcw  = (const float*)d_in[19];
  const float* fcb  = (const float*)d_in[20];
  const float* wih0 = (const float*)d_in[21];
  const float* whh0 = (const float*)d_in[22];
  const float* bih0 = (const float*)d_in[23];
  const float* bhh0 = (const float*)d_in[24];
  const float* wih1 = (const float*)d_in[25];
  const float* whh1 = (const float*)d_in[26];
  const float* bih1 = (const float*)d_in[27];
  const float* bhh1 = (const float*)d_in[28];
  const float* pw   = (const float*)d_in[29];
  const float* pb   = (const float*)d_in[30];
  const float* emb  = (const float*)d_in[31];

  float* ws = (float*)d_ws;
  float* outp = (float*)d_out;

  // state block: h1g(12288 ull) + h2g(12288 ull) + prevg(1408 ull) + bar
  const size_t ST_BYTES = (12288ull + 12288ull + 1408ull) * 8ull + 64ull;
  const size_t needA = (ACO_FL + Z1A_FL) * 4ull + ST_BYTES;  // ~125.8 MB
  int useZ = (ws_size >= needA) ? 1 : 0;
  const int CB = useZ ? 4 : 1;
  const int nchunks = 16 / CB;
  const size_t A_FL  = (size_t)CB * 48 * 512 * 114;
  const size_t BF_FL = (size_t)CB * 510 * 5472;

  float* aco  = ws;                         // [8160][768]
  float* z1aT = ws + ACO_FL;                // [510][3072][16] (path A)
  float* Ac   = ws + ACO_FL;                // conv scratch (aliases z1aT in A)
  float* Bfc  = Ac + A_FL;
  size_t SB   = useZ ? (ACO_FL + Z1A_FL) : (ACO_FL + A_FL + BF_FL);
  ull* h1g    = (ull*)(ws + SB);
  ull* h2g    = h1g + 12288;
  ull* prevg  = h2g + 12288;
  unsigned* bar = (unsigned*)(prevg + 1408);

  for (int ch = 0; ch < nchunks; ++ch) {
    int b0 = ch * CB;
    hipLaunchKernelGGL(conv12_kernel, dim3(CB * 512), dim3(256), 0, stream,
                       mel, c1w, c1b, bn1g, bn1b, bn1m, bn1v,
                       c2w, c2b, bn2g, bn2b, bn2m, bn2v, Ac, b0);
    hipLaunchKernelGGL(conv3_kernel, dim3(CB * 510), dim3(256), 0, stream,
                       Ac, c3w, c3b, bn3g, bn3b, bn3m, bn3v, Bfc);
    int M = CB * 510;
    hipLaunchKernelGGL(gemm_nt, dim3((M + 63) / 64, 12), dim3(256), 0, stream,
                       Bfc, fcw, fcb, (const float*)nullptr,
                       aco + (size_t)b0 * 510 * 768,
                       M, 768, 5472, 5472, 5472, 768, 0);
  }
  if (useZ) {
    // z1aT[t][j][b] = aco[b*510+t] . wih0[j,:768] + bih0[j] + bhh0[j]
    hipLaunchKernelGGL(gemm_nt, dim3(128, 48), dim3(256), 0, stream,
                       aco, wih0, bih0, bhh0, z1aT,
                       8160, 3072, 768, 768, 944, 3072, 1);
  }
  hipLaunchKernelGGL(init_state, dim3(48), dim3(256), 0, stream, h1g, h2g, bar);

  {
    const float* z1aT_c = z1aT;
    const float* aco_c = aco;
    void* args[] = {
      (void*)&z1aT_c, (void*)&whh0, (void*)&wih0, (void*)&wih1, (void*)&whh1,
      (void*)&bih0, (void*)&bhh0, (void*)&bih1, (void*)&bhh1,
      (void*)&pw, (void*)&pb, (void*)&emb,
      (void*)&h1g, (void*)&h2g, (void*)&prevg, (void*)&bar, (void*)&outp,
      (void*)&useZ, (void*)&aco_c
    };
    hipError_t e = hipLaunchCooperativeKernel((const void*)lstm_kernel,
                                              dim3(192), dim3(256), args, 0, stream);
    if (e != hipSuccess) {
      (void)hipGetLastError();
      hipLaunchKernelGGL(lstm_kernel, dim3(192), dim3(256), 0, stream,
                         z1aT_c, whh0, wih0, wih1, whh1, bih0, bhh0, bih1, bhh1,
                         pw, pb, emb, h1g, h2g, prevg, bar, outp, useZ, aco_c);
    }
  }
}

// Round 4
// 43720.926 us; speedup vs baseline: 2.5795x; 1.3344x over previous
//
#include <hip/hip_runtime.h>
#include <math.h>

// ============================================================================
// AR_Transcriber round 4.
// Round-3 LSTM was HBM-refetch-bound: 5 MB/XCD weight working set thrashed the
// 4 MB L2 cyclically (FETCH 13.7 MB/step, dur == FETCH/150GB/s). Fix: weights
// become REGISTER-RESIDENT. Thread (r=gate-row, s=k-chunk) holds 48-float
// slices of whh0/wih0x/wih1/whh1 (+11 prev +48 pw) in VGPRs for all 510 steps.
// h staged in LDS chunked [s][b][48]; partial dots reduced via shfl_xor(16).
// Z1a precompute dropped (x-dot inlined from registers). Projection per-pitch
// (block B<88 owns pitch B) so argmax is block-local.
// ============================================================================

typedef unsigned long long ull;

#define ACO_FL 6266880ull  // 8160*768

__device__ __forceinline__ float sigf(float x) { return 1.0f / (1.0f + expf(-x)); }

__device__ __forceinline__ ull pack2(float x, float y) {
  union { float f[2]; ull u; } c; c.f[0] = x; c.f[1] = y; return c.u;
}
__device__ __forceinline__ float2 unpack2(ull u) {
  union { ull u; float2 v; } c; c.u = u; return c.v;
}
__device__ __forceinline__ ull at_load(const ull* p) {
  return __hip_atomic_load((ull*)p, __ATOMIC_RELAXED, __HIP_MEMORY_SCOPE_AGENT);
}
__device__ __forceinline__ void at_store(ull* p, ull v) {
  __hip_atomic_store(p, v, __ATOMIC_RELAXED, __HIP_MEMORY_SCOPE_AGENT);
}

// Fence-free grid barrier (round-3 validated).
__device__ __forceinline__ void gbar(unsigned* cnt, unsigned target) {
  __syncthreads();
  if (threadIdx.x == 0) {
    __builtin_amdgcn_s_waitcnt(0);
    __atomic_signal_fence(__ATOMIC_SEQ_CST);
    __hip_atomic_fetch_add(cnt, 1u, __ATOMIC_RELAXED, __HIP_MEMORY_SCOPE_AGENT);
    while (__hip_atomic_load(cnt, __ATOMIC_RELAXED, __HIP_MEMORY_SCOPE_AGENT) < target) {
      __builtin_amdgcn_s_sleep(2);
    }
    __atomic_signal_fence(__ATOMIC_SEQ_CST);
  }
  __syncthreads();
}

__device__ __forceinline__ float red16(float v) {
  v += __shfl_xor(v, 1, 16);
  v += __shfl_xor(v, 2, 16);
  v += __shfl_xor(v, 4, 16);
  v += __shfl_xor(v, 8, 16);
  return v;
}

// 48-FMA chunk dot: weights from VGPR array W, data from LDS pointer PTR.
#define CDOT48(W, PTR, RES) do {                                              \
  const float* _p = (PTR);                                                    \
  float _a0 = 0.f, _a1 = 0.f, _a2 = 0.f, _a3 = 0.f;                           \
  _Pragma("unroll")                                                           \
  for (int _i = 0; _i < 48; _i += 16) {                                       \
    float4 _v0 = *(const float4*)(_p + _i);                                   \
    float4 _v1 = *(const float4*)(_p + _i + 4);                               \
    float4 _v2 = *(const float4*)(_p + _i + 8);                               \
    float4 _v3 = *(const float4*)(_p + _i + 12);                              \
    _a0 = fmaf((W)[_i + 0], _v0.x, _a0); _a0 = fmaf((W)[_i + 1], _v0.y, _a0); \
    _a0 = fmaf((W)[_i + 2], _v0.z, _a0); _a0 = fmaf((W)[_i + 3], _v0.w, _a0); \
    _a1 = fmaf((W)[_i + 4], _v1.x, _a1); _a1 = fmaf((W)[_i + 5], _v1.y, _a1); \
    _a1 = fmaf((W)[_i + 6], _v1.z, _a1); _a1 = fmaf((W)[_i + 7], _v1.w, _a1); \
    _a2 = fmaf((W)[_i + 8], _v2.x, _a2); _a2 = fmaf((W)[_i + 9], _v2.y, _a2); \
    _a2 = fmaf((W)[_i +10], _v2.z, _a2); _a2 = fmaf((W)[_i +11], _v2.w, _a2); \
    _a3 = fmaf((W)[_i +12], _v3.x, _a3); _a3 = fmaf((W)[_i +13], _v3.y, _a3); \
    _a3 = fmaf((W)[_i +14], _v3.z, _a3); _a3 = fmaf((W)[_i +15], _v3.w, _a3); \
  }                                                                           \
  RES = (_a0 + _a1) + (_a2 + _a3);                                            \
} while (0)

// Stage one h buffer (ull [16][384]) into hs chunked layout. r=batch, s=chunk.
#define STAGE_H(SRC) do {                                                     \
  const ull* _sp = (SRC) + r * 384 + s * 24;                                  \
  float* _dp = hs + s * 772 + r * 48;                                         \
  _Pragma("unroll")                                                           \
  for (int _q = 0; _q < 24; _q += 2) {                                        \
    float2 _va = unpack2(at_load(_sp + _q));                                  \
    float2 _vb = unpack2(at_load(_sp + _q + 1));                              \
    *(float4*)(_dp + 2 * _q) = make_float4(_va.x, _va.y, _vb.x, _vb.y);       \
  }                                                                           \
} while (0)

// ---------------------------------------------------------------------------
// K1: fused conv1+bn1+relu -> conv2+bn2+relu -> pool(1,2). (unchanged)
// ---------------------------------------------------------------------------
__global__ __launch_bounds__(256) void conv12_kernel(
    const float* __restrict__ mel,
    const float* __restrict__ c1w, const float* __restrict__ c1b,
    const float* __restrict__ bn1g, const float* __restrict__ bn1b,
    const float* __restrict__ bn1m, const float* __restrict__ bn1v,
    const float* __restrict__ c2w, const float* __restrict__ c2b,
    const float* __restrict__ bn2g, const float* __restrict__ bn2b,
    const float* __restrict__ bn2m, const float* __restrict__ bn2v,
    float* __restrict__ A, int b0)
{
  __shared__ float melS[5 * 232];
  __shared__ float x1S[12 * 3 * 232];
  __shared__ float wS[48 * 12 * 9];
  const int tid = threadIdx.x;
  const int bl = blockIdx.x >> 9;
  const int b = b0 + bl;
  const int t = blockIdx.x & 511;

  for (int idx = tid; idx < 5 * 232; idx += 256) {
    int rr = idx / 232, cc = idx - rr * 232;
    int r = t - 2 + rr, w = cc - 1;
    float v = 0.f;
    if (r >= 0 && r < 512 && w >= 0 && w < 229) v = mel[(b * 512 + r) * 229 + w];
    melS[idx] = v;
  }

  float accA[22], accB[22];
#pragma unroll
  for (int i = 0; i < 22; ++i) { accA[i] = 0.f; accB[i] = 0.f; }
  __syncthreads();

  for (int icc = 0; icc < 4; ++icc) {
    if (icc) __syncthreads();
    for (int idx = tid; idx < 12 * 3 * 232; idx += 256) {
      int cl = idx / (3 * 232);
      int rem = idx - cl * (3 * 232);
      int rr = rem / 232, cc = rem - rr * 232;
      int c = icc * 12 + cl;
      int r1 = t - 1 + rr, w = cc - 1;
      float v = 0.f;
      if (r1 >= 0 && r1 < 512 && w >= 0 && w < 229) {
        const float* cw = c1w + c * 9;
        const float* m0 = melS + rr * 232 + cc - 1;
        float s = m0[0] * cw[0] + m0[1] * cw[1] + m0[2] * cw[2]
                + m0[232] * cw[3] + m0[233] * cw[4] + m0[234] * cw[5]
                + m0[464] * cw[6] + m0[465] * cw[7] + m0[466] * cw[8];
        s += c1b[c];
        float sc = bn1g[c] * rsqrtf(bn1v[c] + 1e-5f);
        v = fmaxf(s * sc + (bn1b[c] - bn1m[c] * sc), 0.f);
      }
      x1S[idx] = v;
    }
    for (int idx = tid; idx < 48 * 12 * 9; idx += 256) {
      int oc = idx / 108, rem = idx - oc * 108;
      wS[idx] = c2w[(oc * 48 + icc * 12) * 9 + rem];
    }
    __syncthreads();
    for (int i = 0; i < 22; ++i) {
      int oidx = tid + i * 256;
      if (oidx >= 5472) break;
      int oc = oidx / 114, wp = oidx - oc * 114;
      int w0 = 2 * wp;
      float a0 = accA[i], a1 = accB[i];
      const float* wp9 = wS + oc * 108;
      for (int icl = 0; icl < 12; ++icl) {
#pragma unroll
        for (int a = 0; a < 3; ++a) {
          const float* xr = x1S + (icl * 3 + a) * 232 + w0;
          float x0 = xr[0], x1 = xr[1], x2 = xr[2], x3 = xr[3];
          float wA = wp9[icl * 9 + a * 3 + 0];
          float wB = wp9[icl * 9 + a * 3 + 1];
          float wC = wp9[icl * 9 + a * 3 + 2];
          a0 = fmaf(x0, wA, a0); a0 = fmaf(x1, wB, a0); a0 = fmaf(x2, wC, a0);
          a1 = fmaf(x1, wA, a1); a1 = fmaf(x2, wB, a1); a1 = fmaf(x3, wC, a1);
        }
      }
      accA[i] = a0; accB[i] = a1;
    }
  }
  for (int i = 0; i < 22; ++i) {
    int oidx = tid + i * 256;
    if (oidx >= 5472) break;
    int oc = oidx / 114, wp = oidx - oc * 114;
    float sc = bn2g[oc] * rsqrtf(bn2v[oc] + 1e-5f);
    float sh = bn2b[oc] - bn2m[oc] * sc;
    float v0 = fmaxf((accA[i] + c2b[oc]) * sc + sh, 0.f);
    float v1 = fmaxf((accB[i] + c2b[oc]) * sc + sh, 0.f);
    A[((bl * 48 + oc) * 512 + t) * 114 + wp] = fmaxf(v0, v1);
  }
}

// ---------------------------------------------------------------------------
// K2: conv3+bn3+relu+pool(1,2); GEMM-ready output. (unchanged)
// ---------------------------------------------------------------------------
__global__ __launch_bounds__(256) void conv3_kernel(
    const float* __restrict__ A,
    const float* __restrict__ c3w, const float* __restrict__ c3b,
    const float* __restrict__ bn3g, const float* __restrict__ bn3b,
    const float* __restrict__ bn3m, const float* __restrict__ bn3v,
    float* __restrict__ Bf)
{
  __shared__ float aS[16 * 3 * 116];
  __shared__ float wS[48 * 16 * 9];
  const int tid = threadIdx.x;
  const int bl = blockIdx.x / 510;
  const int t = blockIdx.x - bl * 510;

  for (int ocg = 0; ocg < 2; ++ocg) {
    float accA[11], accB[11];
#pragma unroll
    for (int i = 0; i < 11; ++i) { accA[i] = 0.f; accB[i] = 0.f; }
    for (int icc = 0; icc < 3; ++icc) {
      __syncthreads();
      for (int idx = tid; idx < 16 * 3 * 116; idx += 256) {
        int cl = idx / 348, rem = idx - cl * 348;
        int rr = rem / 116, cc = rem - rr * 116;
        int w = cc - 1;
        float v = 0.f;
        if (w >= 0 && w < 114) v = A[((bl * 48 + icc * 16 + cl) * 512 + t + rr) * 114 + w];
        aS[idx] = v;
      }
      for (int idx = tid; idx < 48 * 16 * 9; idx += 256) {
        int ocl = idx / 144, rem = idx - ocl * 144;
        wS[idx] = c3w[((ocg * 48 + ocl) * 48 + icc * 16) * 9 + rem];
      }
      __syncthreads();
      for (int i = 0; i < 11; ++i) {
        int oidx = tid + i * 256;
        if (oidx >= 2736) break;
        int ocl = oidx / 57, wp = oidx - ocl * 57;
        int w0 = 2 * wp;
        float a0 = accA[i], a1 = accB[i];
        const float* wb = wS + ocl * 144;
        for (int icl = 0; icl < 16; ++icl) {
#pragma unroll
          for (int a = 0; a < 3; ++a) {
            const float* xr = aS + (icl * 3 + a) * 116 + w0;
            float x0 = xr[0], x1 = xr[1], x2 = xr[2], x3 = xr[3];
            float wA = wb[icl * 9 + a * 3 + 0];
            float wB = wb[icl * 9 + a * 3 + 1];
            float wC = wb[icl * 9 + a * 3 + 2];
            a0 = fmaf(x0, wA, a0); a0 = fmaf(x1, wB, a0); a0 = fmaf(x2, wC, a0);
            a1 = fmaf(x1, wA, a1); a1 = fmaf(x2, wB, a1); a1 = fmaf(x3, wC, a1);
          }
        }
        accA[i] = a0; accB[i] = a1;
      }
    }
    for (int i = 0; i < 11; ++i) {
      int oidx = tid + i * 256;
      if (oidx >= 2736) break;
      int ocl = oidx / 57, wp = oidx - ocl * 57;
      int oc = ocg * 48 + ocl;
      float sc = bn3g[oc] * rsqrtf(bn3v[oc] + 1e-5f);
      float sh = bn3b[oc] - bn3m[oc] * sc;
      float v0 = fmaxf((accA[i] + c3b[oc]) * sc + sh, 0.f);
      float v1 = fmaxf((accB[i] + c3b[oc]) * sc + sh, 0.f);
      Bf[(size_t)(bl * 510 + t) * 5472 + oc * 57 + wp] = fmaxf(v0, v1);
    }
  }
}

// ---------------------------------------------------------------------------
// K3: fp32 NT GEMM  C[M,N] = A * B^T + bias. (FC only now)
// ---------------------------------------------------------------------------
__global__ __launch_bounds__(256) void gemm_nt(
    const float* __restrict__ Am, const float* __restrict__ Bm,
    const float* __restrict__ bias, float* __restrict__ C,
    int M, int N, int K, int lda, int ldb, int ldc)
{
  __shared__ float As[64 * 33];
  __shared__ float Bs[64 * 33];
  const int tid = threadIdx.x;
  const int m0 = blockIdx.x * 64, n0 = blockIdx.y * 64;
  const int tx = tid & 15, ty = tid >> 4;
  const int kq = (tid & 7) * 4, rw = tid >> 3;
  float acc[4][4];
#pragma unroll
  for (int i = 0; i < 4; ++i)
#pragma unroll
    for (int j = 0; j < 4; ++j) acc[i][j] = 0.f;

  for (int k0 = 0; k0 < K; k0 += 32) {
    int m1 = m0 + rw, m2 = m1 + 32;
    float4 va = make_float4(0.f, 0.f, 0.f, 0.f), vb = va;
    if (m1 < M) va = *(const float4*)(Am + (size_t)m1 * lda + k0 + kq);
    if (m2 < M) vb = *(const float4*)(Am + (size_t)m2 * lda + k0 + kq);
    float4 wa = *(const float4*)(Bm + (size_t)(n0 + rw) * ldb + k0 + kq);
    float4 wb = *(const float4*)(Bm + (size_t)(n0 + rw + 32) * ldb + k0 + kq);
    As[rw * 33 + kq + 0] = va.x; As[rw * 33 + kq + 1] = va.y;
    As[rw * 33 + kq + 2] = va.z; As[rw * 33 + kq + 3] = va.w;
    As[(rw + 32) * 33 + kq + 0] = vb.x; As[(rw + 32) * 33 + kq + 1] = vb.y;
    As[(rw + 32) * 33 + kq + 2] = vb.z; As[(rw + 32) * 33 + kq + 3] = vb.w;
    Bs[rw * 33 + kq + 0] = wa.x; Bs[rw * 33 + kq + 1] = wa.y;
    Bs[rw * 33 + kq + 2] = wa.z; Bs[rw * 33 + kq + 3] = wa.w;
    Bs[(rw + 32) * 33 + kq + 0] = wb.x; Bs[(rw + 32) * 33 + kq + 1] = wb.y;
    Bs[(rw + 32) * 33 + kq + 2] = wb.z; Bs[(rw + 32) * 33 + kq + 3] = wb.w;
    __syncthreads();
#pragma unroll 8
    for (int k = 0; k < 32; ++k) {
      float av[4], bv[4];
#pragma unroll
      for (int i = 0; i < 4; ++i) av[i] = As[(ty * 4 + i) * 33 + k];
#pragma unroll
      for (int j = 0; j < 4; ++j) bv[j] = Bs[(tx * 4 + j) * 33 + k];
#pragma unroll
      for (int i = 0; i < 4; ++i)
#pragma unroll
        for (int j = 0; j < 4; ++j) acc[i][j] = fmaf(av[i], bv[j], acc[i][j]);
    }
    __syncthreads();
  }
#pragma unroll
  for (int i = 0; i < 4; ++i) {
    int m = m0 + ty * 4 + i;
    if (m >= M) continue;
#pragma unroll
    for (int j = 0; j < 4; ++j) {
      int n = n0 + tx * 4 + j;
      C[(size_t)m * ldc + n] = acc[i][j] + bias[n];
    }
  }
}

// ---------------------------------------------------------------------------
__global__ void init_state(ull* __restrict__ h1g, ull* __restrict__ h2g,
                           unsigned* __restrict__ bar) {
  int gid = blockIdx.x * 256 + threadIdx.x;
  if (gid < 12288) { at_store(h1g + gid, 0ull); at_store(h2g + gid, 0ull); }
  if (gid == 0) __hip_atomic_store(bar, 0u, __ATOMIC_RELAXED, __HIP_MEMORY_SCOPE_AGENT);
}

// ---------------------------------------------------------------------------
// K6: persistent LSTM, register-resident weights.
// 192 blocks x 256 threads (coop). Block owns 4 hidden units (16 gate-rows).
// Thread (r = gate-row 0..15, s = k-chunk 0..15) holds w slices in VGPRs.
// ---------------------------------------------------------------------------
__global__ __launch_bounds__(256, 1) void lstm_kernel(
    const float* __restrict__ aco,   // [16][510][768]
    const float* __restrict__ whh0,  // [3072][768]
    const float* __restrict__ wih0,  // [3072][944]
    const float* __restrict__ wih1,  // [3072][768]
    const float* __restrict__ whh1,  // [3072][768]
    const float* __restrict__ bih0, const float* __restrict__ bhh0,
    const float* __restrict__ bih1, const float* __restrict__ bhh1,
    const float* __restrict__ pw,    // [440][768]
    const float* __restrict__ pb,
    const float* __restrict__ emb,   // [5][2]
    ull* __restrict__ h1g,           // [2][16][384] packed pairs
    ull* __restrict__ h2g,
    ull* __restrict__ prevg,         // [16][88] packed emb pairs
    unsigned* __restrict__ bar,
    float* __restrict__ out)         // [16][510][440]
{
  __shared__ float hs[16 * 772];     // chunked [s][b][48], stride 772
  __shared__ float prevs[16 * 177];  // chunked [s][b][11], stride 177
  __shared__ float zl[16 * 17];      // [row][b]
  __shared__ float harr[64];
  __shared__ float embS[10];
  const int tid = threadIdx.x;
  const int s = tid & 15;            // k-chunk
  const int r = tid >> 4;            // gate-row (dots) / batch (staging)
  const int uB = blockIdx.x * 4;
  const int j = (r >> 2) * 768 + uB + (r & 3);

  // ---- one-time register weight load ----
  float wx[48], w0[48], w1[48], w2[48], wp[11], pwr[48];
  {
    const float* p = wih0 + (size_t)j * 944 + 48 * s;
#pragma unroll
    for (int i = 0; i < 48; i += 4) {
      float4 v = *(const float4*)(p + i);
      wx[i] = v.x; wx[i+1] = v.y; wx[i+2] = v.z; wx[i+3] = v.w;
    }
    p = whh0 + (size_t)j * 768 + 48 * s;
#pragma unroll
    for (int i = 0; i < 48; i += 4) {
      float4 v = *(const float4*)(p + i);
      w0[i] = v.x; w0[i+1] = v.y; w0[i+2] = v.z; w0[i+3] = v.w;
    }
    p = wih1 + (size_t)j * 768 + 48 * s;
#pragma unroll
    for (int i = 0; i < 48; i += 4) {
      float4 v = *(const float4*)(p + i);
      w1[i] = v.x; w1[i+1] = v.y; w1[i+2] = v.z; w1[i+3] = v.w;
    }
    p = whh1 + (size_t)j * 768 + 48 * s;
#pragma unroll
    for (int i = 0; i < 48; i += 4) {
      float4 v = *(const float4*)(p + i);
      w2[i] = v.x; w2[i+1] = v.y; w2[i+2] = v.z; w2[i+3] = v.w;
    }
    const float* pp = wih0 + (size_t)j * 944 + 768 + 11 * s;
#pragma unroll
    for (int i = 0; i < 11; ++i) wp[i] = pp[i];
  }
  const bool pv = (blockIdx.x < 88) && (r < 5);
  const int prow = blockIdx.x * 5 + r;
  float pbv = 0.f;
  if (pv) {
    const float* p = pw + (size_t)prow * 768 + 48 * s;
#pragma unroll
    for (int i = 0; i < 48; i += 4) {
      float4 v = *(const float4*)(p + i);
      pwr[i] = v.x; pwr[i+1] = v.y; pwr[i+2] = v.z; pwr[i+3] = v.w;
    }
    pbv = pb[prow];
  } else {
#pragma unroll
    for (int i = 0; i < 48; ++i) pwr[i] = 0.f;
  }
  // cell-thread constants (tid<64: ul = tid>>4, b = tid&15)
  float bl1[4], bl2[4], c1 = 0.f, c2 = 0.f;
  if (tid < 64) {
    int ul = tid >> 4;
#pragma unroll
    for (int g = 0; g < 4; ++g) {
      int jj = g * 768 + uB + ul;
      bl1[g] = bih0[jj] + bhh0[jj];
      bl2[g] = bih1[jj] + bhh1[jj];
    }
  }
  if (tid < 10) embS[tid] = emb[tid];

  unsigned nb = 0;
  const unsigned NG = gridDim.x;

  for (int t = 0; t < 510; ++t) {
    const int wbuf = t & 1, rbuf = wbuf ^ 1;
    // ============ PH1a: stage x(t), x-dot ============
    {
      const float* xr = aco + ((size_t)r * 510 + t) * 768 + 48 * s;
      float* dst = hs + s * 772 + r * 48;
#pragma unroll
      for (int i = 0; i < 48; i += 4) *(float4*)(dst + i) = *(const float4*)(xr + i);
    }
    __syncthreads();
    for (int b = 0; b < 16; ++b) {
      float p; CDOT48(wx, hs + s * 772 + b * 48, p);
      p = red16(p);
      if (s == 0) zl[r * 17 + b] = p;
    }
    __syncthreads();
    // ============ PH1b: stage h1(t-1) + prevs, recurrent dot ============
    STAGE_H(h1g + rbuf * 6144);
    if (t == 0) {
      float* pd = prevs + s * 177 + r * 11;
#pragma unroll
      for (int i = 0; i < 11; ++i) pd[i] = 0.f;
    } else {
      const ull* pg = prevg + r * 88;
      float* pd = prevs + s * 177 + r * 11;
      int d0 = 11 * s;
#pragma unroll
      for (int i = 0; i < 11; ++i) {
        int d = d0 + i;
        float2 e = unpack2(at_load(pg + (d >> 1)));
        pd[i] = (d & 1) ? e.y : e.x;
      }
    }
    __syncthreads();
    for (int b = 0; b < 16; ++b) {
      float p; CDOT48(w0, hs + s * 772 + b * 48, p);
      const float* pvv = prevs + s * 177 + b * 11;
#pragma unroll
      for (int i = 0; i < 11; ++i) p = fmaf(wp[i], pvv[i], p);
      p = red16(p);
      if (s == 0) zl[r * 17 + b] += p;
    }
    __syncthreads();
    if (tid < 64) {
      int ul = tid >> 4, bb = tid & 15;
      float zi = zl[(0 * 4 + ul) * 17 + bb] + bl1[0];
      float zf = zl[(1 * 4 + ul) * 17 + bb] + bl1[1];
      float zg = zl[(2 * 4 + ul) * 17 + bb] + bl1[2];
      float zo = zl[(3 * 4 + ul) * 17 + bb] + bl1[3];
      c1 = sigf(zf) * c1 + sigf(zi) * tanhf(zg);
      harr[tid] = sigf(zo) * tanhf(c1);
    }
    __syncthreads();
    if (tid < 32) {
      int q = tid >> 4, bb = tid & 15;
      at_store(h1g + wbuf * 6144 + bb * 384 + blockIdx.x * 2 + q,
               pack2(harr[(2 * q) * 16 + bb], harr[(2 * q + 1) * 16 + bb]));
    }
    ++nb; gbar(bar, nb * NG);
    // ============ PH2: h2 cell ============
    STAGE_H(h1g + wbuf * 6144);
    __syncthreads();
    for (int b = 0; b < 16; ++b) {
      float p; CDOT48(w1, hs + s * 772 + b * 48, p);
      p = red16(p);
      if (s == 0) zl[r * 17 + b] = p;
    }
    __syncthreads();
    STAGE_H(h2g + rbuf * 6144);
    __syncthreads();
    for (int b = 0; b < 16; ++b) {
      float p; CDOT48(w2, hs + s * 772 + b * 48, p);
      p = red16(p);
      if (s == 0) zl[r * 17 + b] += p;
    }
    __syncthreads();
    if (tid < 64) {
      int ul = tid >> 4, bb = tid & 15;
      float zi = zl[(0 * 4 + ul) * 17 + bb] + bl2[0];
      float zf = zl[(1 * 4 + ul) * 17 + bb] + bl2[1];
      float zg = zl[(2 * 4 + ul) * 17 + bb] + bl2[2];
      float zo = zl[(3 * 4 + ul) * 17 + bb] + bl2[3];
      c2 = sigf(zf) * c2 + sigf(zi) * tanhf(zg);
      harr[tid] = sigf(zo) * tanhf(c2);
    }
    __syncthreads();
    if (tid < 32) {
      int q = tid >> 4, bb = tid & 15;
      at_store(h2g + wbuf * 6144 + bb * 384 + blockIdx.x * 2 + q,
               pack2(harr[(2 * q) * 16 + bb], harr[(2 * q + 1) * 16 + bb]));
    }
    ++nb; gbar(bar, nb * NG);
    // ============ PH3: projection + argmax (blocks < 88, pitch each) ====
    if (blockIdx.x < 88) {
      STAGE_H(h2g + wbuf * 6144);
      __syncthreads();
      for (int b = 0; b < 16; ++b) {
        float p; CDOT48(pwr, hs + s * 772 + b * 48, p);
        p = red16(p);
        if (pv && s == 0) {
          float lg = p + pbv;
          out[((size_t)b * 510 + t) * 440 + prow] = lg;
          zl[r * 17 + b] = lg;
        }
      }
      __syncthreads();
      if (tid < 16) {
        float best = zl[0 * 17 + tid]; int bi = 0;
#pragma unroll
        for (int c = 1; c < 5; ++c) {
          float v = zl[c * 17 + tid];
          if (v > best) { best = v; bi = c; }
        }
        at_store(prevg + tid * 88 + blockIdx.x, pack2(embS[bi * 2], embS[bi * 2 + 1]));
      }
    }
    ++nb; gbar(bar, nb * NG);
  }
}

// ---------------------------------------------------------------------------
extern "C" void kernel_launch(void* const* d_in, const int* in_sizes, int n_in,
                              void* d_out, int out_size, void* d_ws, size_t ws_size,
                              hipStream_t stream) {
  (void)in_sizes; (void)n_in; (void)out_size;
  const float* mel  = (const float*)d_in[0];
  const float* c1w  = (const float*)d_in[1];
  const float* c1b  = (const float*)d_in[2];
  const float* c2w  = (const float*)d_in[3];
  const float* c2b  = (const float*)d_in[4];
  const float* c3w  = (const float*)d_in[5];
  const float* c3b  = (const float*)d_in[6];
  const float* bn1g = (const float*)d_in[7];
  const float* bn1b = (const float*)d_in[8];
  const float* bn1m = (const float*)d_in[9];
  const float* bn1v = (const float*)d_in[10];
  const float* bn2g = (const float*)d_in[11];
  const float* bn2b = (const float*)d_in[12];
  const float* bn2m = (const float*)d_in[13];
  const float* bn2v = (const float*)d_in[14];
  const float* bn3g = (const float*)d_in[15];
  const float* bn3b = (const float*)d_in[16];
  const float* bn3m = (const float*)d_in[17];
  const float* bn3v = (const float*)d_in[18];
  const float* fcw  = (const float*)d_in[19];
  const float* fcb  = (const float*)d_in[20];
  const float* wih0 = (const float*)d_in[21];
  const float* whh0 = (const float*)d_in[22];
  const float* bih0 = (const float*)d_in[23];
  const float* bhh0 = (const float*)d_in[24];
  const float* wih1 = (const float*)d_in[25];
  const float* whh1 = (const float*)d_in[26];
  const float* bih1 = (const float*)d_in[27];
  const float* bhh1 = (const float*)d_in[28];
  const float* pw   = (const float*)d_in[29];
  const float* pb   = (const float*)d_in[30];
  const float* emb  = (const float*)d_in[31];

  float* ws = (float*)d_ws;
  float* outp = (float*)d_out;

  const size_t ST_ULL = 12288ull + 12288ull + 1408ull;
  // pick conv chunking by ws_size (constant across calls -> graph-safe)
  int CB = 1;
  for (int cb = 4; cb >= 1; cb >>= 1) {
    size_t need = (ACO_FL + (size_t)cb * 48 * 512 * 114 + (size_t)cb * 510 * 5472) * 4
                + ST_ULL * 8 + 256;
    if (ws_size >= need) { CB = cb; break; }
  }
  const int nchunks = 16 / CB;
  const size_t A_FL  = (size_t)CB * 48 * 512 * 114;
  const size_t BF_FL = (size_t)CB * 510 * 5472;

  float* aco = ws;
  float* Ac  = ws + ACO_FL;
  float* Bfc = Ac + A_FL;
  ull* h1g   = (ull*)(Bfc + BF_FL);
  ull* h2g   = h1g + 12288;
  ull* prevg = h2g + 12288;
  unsigned* bar = (unsigned*)(prevg + 1408);

  for (int ch = 0; ch < nchunks; ++ch) {
    int b0 = ch * CB;
    hipLaunchKernelGGL(conv12_kernel, dim3(CB * 512), dim3(256), 0, stream,
                       mel, c1w, c1b, bn1g, bn1b, bn1m, bn1v,
                       c2w, c2b, bn2g, bn2b, bn2m, bn2v, Ac, b0);
    hipLaunchKernelGGL(conv3_kernel, dim3(CB * 510), dim3(256), 0, stream,
                       Ac, c3w, c3b, bn3g, bn3b, bn3m, bn3v, Bfc);
    int M = CB * 510;
    hipLaunchKernelGGL(gemm_nt, dim3((M + 63) / 64, 12), dim3(256), 0, stream,
                       Bfc, fcw, fcb, aco + (size_t)b0 * 510 * 768,
                       M, 768, 5472, 5472, 5472, 768);
  }
  hipLaunchKernelGGL(init_state, dim3(48), dim3(256), 0, stream, h1g, h2g, bar);

  {
    void* args[] = {
      (void*)&aco, (void*)&whh0, (void*)&wih0, (void*)&wih1, (void*)&whh1,
      (void*)&bih0, (void*)&bhh0, (void*)&bih1, (void*)&bhh1,
      (void*)&pw, (void*)&pb, (void*)&emb,
      (void*)&h1g, (void*)&h2g, (void*)&prevg, (void*)&bar, (void*)&outp
    };
    hipError_t e = hipLaunchCooperativeKernel((const void*)lstm_kernel,
                                              dim3(192), dim3(256), args, 0, stream);
    if (e != hipSuccess) {
      (void)hipGetLastError();
      hipLaunchKernelGGL(lstm_kernel, dim3(192), dim3(256), 0, stream,
                         aco, whh0, wih0, wih1, whh1, bih0, bhh0, bih1, bhh1,
                         pw, pb, emb, h1g, h2g, prevg, bar, outp);
    }
  }
}

// Round 5
// 40466.977 us; speedup vs baseline: 2.7870x; 1.0804x over previous
//
#include <hip/hip_runtime.h>
#include <math.h>

// ============================================================================
// AR_Transcriber round 5.
// Round-4 LSTM was GRID-BARRIER-bound: single atomic counter -> 192 serialized
// RMWs on one cache line + 191 pollers on the same line ~= 21 us/barrier
// (32 ms of the 36 ms dispatch; VALUBusy 8%, HBM 0.1%).
// Fix: hierarchical barrier -- 8 arrival counters on separate 64B lines
// (<=24 RMWs each, parallel across lines), master block polls the 8 and
// publishes a monotone release epoch on its own line; all others poll only
// the release line (reads, no RMW convoy). Everything else identical to r4
// (register-resident weights, relaxed-atomic state exchange).
// ============================================================================

typedef unsigned long long ull;

#define ACO_FL 6266880ull  // 8160*768

__device__ __forceinline__ float sigf(float x) { return 1.0f / (1.0f + expf(-x)); }

__device__ __forceinline__ ull pack2(float x, float y) {
  union { float f[2]; ull u; } c; c.f[0] = x; c.f[1] = y; return c.u;
}
__device__ __forceinline__ float2 unpack2(ull u) {
  union { ull u; float2 v; } c; c.u = u; return c.v;
}
__device__ __forceinline__ ull at_load(const ull* p) {
  return __hip_atomic_load((ull*)p, __ATOMIC_RELAXED, __HIP_MEMORY_SCOPE_AGENT);
}
__device__ __forceinline__ void at_store(ull* p, ull v) {
  __hip_atomic_store(p, v, __ATOMIC_RELAXED, __HIP_MEMORY_SCOPE_AGENT);
}

// Hierarchical fence-free grid barrier.
// bar layout (unsigned): [0..127] 8 arrival counters, 16-u32 (64B) apart;
//                        [128]    release epoch (own line).
__device__ __forceinline__ void gbar(unsigned* bar, unsigned nb, unsigned NG) {
  __syncthreads();
  if (threadIdx.x == 0) {
    __builtin_amdgcn_s_waitcnt(0);
    __atomic_signal_fence(__ATOMIC_SEQ_CST);
    __hip_atomic_fetch_add(bar + (blockIdx.x & 7) * 16, 1u,
                           __ATOMIC_RELAXED, __HIP_MEMORY_SCOPE_AGENT);
    unsigned* rel = bar + 128;
    if (blockIdx.x == 0) {
      const unsigned target = nb * NG;
      for (;;) {
        unsigned s0 = 0;
#pragma unroll
        for (int i = 0; i < 8; ++i)
          s0 += __hip_atomic_load(bar + i * 16, __ATOMIC_RELAXED,
                                  __HIP_MEMORY_SCOPE_AGENT);
        if (s0 >= target) break;
        __builtin_amdgcn_s_sleep(1);
      }
      __hip_atomic_store(rel, nb, __ATOMIC_RELAXED, __HIP_MEMORY_SCOPE_AGENT);
    } else {
      while (__hip_atomic_load(rel, __ATOMIC_RELAXED,
                               __HIP_MEMORY_SCOPE_AGENT) < nb) {
        __builtin_amdgcn_s_sleep(1);
      }
    }
    __atomic_signal_fence(__ATOMIC_SEQ_CST);
  }
  __syncthreads();
}

__device__ __forceinline__ float red16(float v) {
  v += __shfl_xor(v, 1, 16);
  v += __shfl_xor(v, 2, 16);
  v += __shfl_xor(v, 4, 16);
  v += __shfl_xor(v, 8, 16);
  return v;
}

// 48-FMA chunk dot: weights from VGPR array W, data from LDS pointer PTR.
#define CDOT48(W, PTR, RES) do {                                              \
  const float* _p = (PTR);                                                    \
  float _a0 = 0.f, _a1 = 0.f, _a2 = 0.f, _a3 = 0.f;                           \
  _Pragma("unroll")                                                           \
  for (int _i = 0; _i < 48; _i += 16) {                                       \
    float4 _v0 = *(const float4*)(_p + _i);                                   \
    float4 _v1 = *(const float4*)(_p + _i + 4);                               \
    float4 _v2 = *(const float4*)(_p + _i + 8);                               \
    float4 _v3 = *(const float4*)(_p + _i + 12);                              \
    _a0 = fmaf((W)[_i + 0], _v0.x, _a0); _a0 = fmaf((W)[_i + 1], _v0.y, _a0); \
    _a0 = fmaf((W)[_i + 2], _v0.z, _a0); _a0 = fmaf((W)[_i + 3], _v0.w, _a0); \
    _a1 = fmaf((W)[_i + 4], _v1.x, _a1); _a1 = fmaf((W)[_i + 5], _v1.y, _a1); \
    _a1 = fmaf((W)[_i + 6], _v1.z, _a1); _a1 = fmaf((W)[_i + 7], _v1.w, _a1); \
    _a2 = fmaf((W)[_i + 8], _v2.x, _a2); _a2 = fmaf((W)[_i + 9], _v2.y, _a2); \
    _a2 = fmaf((W)[_i +10], _v2.z, _a2); _a2 = fmaf((W)[_i +11], _v2.w, _a2); \
    _a3 = fmaf((W)[_i +12], _v3.x, _a3); _a3 = fmaf((W)[_i +13], _v3.y, _a3); \
    _a3 = fmaf((W)[_i +14], _v3.z, _a3); _a3 = fmaf((W)[_i +15], _v3.w, _a3); \
  }                                                                           \
  RES = (_a0 + _a1) + (_a2 + _a3);                                            \
} while (0)

// Stage one h buffer (ull [16][384]) into hs chunked layout. r=batch, s=chunk.
#define STAGE_H(SRC) do {                                                     \
  const ull* _sp = (SRC) + r * 384 + s * 24;                                  \
  float* _dp = hs + s * 772 + r * 48;                                         \
  _Pragma("unroll")                                                           \
  for (int _q = 0; _q < 24; _q += 2) {                                        \
    float2 _va = unpack2(at_load(_sp + _q));                                  \
    float2 _vb = unpack2(at_load(_sp + _q + 1));                              \
    *(float4*)(_dp + 2 * _q) = make_float4(_va.x, _va.y, _vb.x, _vb.y);       \
  }                                                                           \
} while (0)

// ---------------------------------------------------------------------------
// K1: fused conv1+bn1+relu -> conv2+bn2+relu -> pool(1,2). (unchanged)
// ---------------------------------------------------------------------------
__global__ __launch_bounds__(256) void conv12_kernel(
    const float* __restrict__ mel,
    const float* __restrict__ c1w, const float* __restrict__ c1b,
    const float* __restrict__ bn1g, const float* __restrict__ bn1b,
    const float* __restrict__ bn1m, const float* __restrict__ bn1v,
    const float* __restrict__ c2w, const float* __restrict__ c2b,
    const float* __restrict__ bn2g, const float* __restrict__ bn2b,
    const float* __restrict__ bn2m, const float* __restrict__ bn2v,
    float* __restrict__ A, int b0)
{
  __shared__ float melS[5 * 232];
  __shared__ float x1S[12 * 3 * 232];
  __shared__ float wS[48 * 12 * 9];
  const int tid = threadIdx.x;
  const int bl = blockIdx.x >> 9;
  const int b = b0 + bl;
  const int t = blockIdx.x & 511;

  for (int idx = tid; idx < 5 * 232; idx += 256) {
    int rr = idx / 232, cc = idx - rr * 232;
    int r = t - 2 + rr, w = cc - 1;
    float v = 0.f;
    if (r >= 0 && r < 512 && w >= 0 && w < 229) v = mel[(b * 512 + r) * 229 + w];
    melS[idx] = v;
  }

  float accA[22], accB[22];
#pragma unroll
  for (int i = 0; i < 22; ++i) { accA[i] = 0.f; accB[i] = 0.f; }
  __syncthreads();

  for (int icc = 0; icc < 4; ++icc) {
    if (icc) __syncthreads();
    for (int idx = tid; idx < 12 * 3 * 232; idx += 256) {
      int cl = idx / (3 * 232);
      int rem = idx - cl * (3 * 232);
      int rr = rem / 232, cc = rem - rr * 232;
      int c = icc * 12 + cl;
      int r1 = t - 1 + rr, w = cc - 1;
      float v = 0.f;
      if (r1 >= 0 && r1 < 512 && w >= 0 && w < 229) {
        const float* cw = c1w + c * 9;
        const float* m0 = melS + rr * 232 + cc - 1;
        float s = m0[0] * cw[0] + m0[1] * cw[1] + m0[2] * cw[2]
                + m0[232] * cw[3] + m0[233] * cw[4] + m0[234] * cw[5]
                + m0[464] * cw[6] + m0[465] * cw[7] + m0[466] * cw[8];
        s += c1b[c];
        float sc = bn1g[c] * rsqrtf(bn1v[c] + 1e-5f);
        v = fmaxf(s * sc + (bn1b[c] - bn1m[c] * sc), 0.f);
      }
      x1S[idx] = v;
    }
    for (int idx = tid; idx < 48 * 12 * 9; idx += 256) {
      int oc = idx / 108, rem = idx - oc * 108;
      wS[idx] = c2w[(oc * 48 + icc * 12) * 9 + rem];
    }
    __syncthreads();
    for (int i = 0; i < 22; ++i) {
      int oidx = tid + i * 256;
      if (oidx >= 5472) break;
      int oc = oidx / 114, wp = oidx - oc * 114;
      int w0 = 2 * wp;
      float a0 = accA[i], a1 = accB[i];
      const float* wp9 = wS + oc * 108;
      for (int icl = 0; icl < 12; ++icl) {
#pragma unroll
        for (int a = 0; a < 3; ++a) {
          const float* xr = x1S + (icl * 3 + a) * 232 + w0;
          float x0 = xr[0], x1 = xr[1], x2 = xr[2], x3 = xr[3];
          float wA = wp9[icl * 9 + a * 3 + 0];
          float wB = wp9[icl * 9 + a * 3 + 1];
          float wC = wp9[icl * 9 + a * 3 + 2];
          a0 = fmaf(x0, wA, a0); a0 = fmaf(x1, wB, a0); a0 = fmaf(x2, wC, a0);
          a1 = fmaf(x1, wA, a1); a1 = fmaf(x2, wB, a1); a1 = fmaf(x3, wC, a1);
        }
      }
      accA[i] = a0; accB[i] = a1;
    }
  }
  for (int i = 0; i < 22; ++i) {
    int oidx = tid + i * 256;
    if (oidx >= 5472) break;
    int oc = oidx / 114, wp = oidx - oc * 114;
    float sc = bn2g[oc] * rsqrtf(bn2v[oc] + 1e-5f);
    float sh = bn2b[oc] - bn2m[oc] * sc;
    float v0 = fmaxf((accA[i] + c2b[oc]) * sc + sh, 0.f);
    float v1 = fmaxf((accB[i] + c2b[oc]) * sc + sh, 0.f);
    A[((bl * 48 + oc) * 512 + t) * 114 + wp] = fmaxf(v0, v1);
  }
}

// ---------------------------------------------------------------------------
// K2: conv3+bn3+relu+pool(1,2); GEMM-ready output. (unchanged)
// ---------------------------------------------------------------------------
__global__ __launch_bounds__(256) void conv3_kernel(
    const float* __restrict__ A,
    const float* __restrict__ c3w, const float* __restrict__ c3b,
    const float* __restrict__ bn3g, const float* __restrict__ bn3b,
    const float* __restrict__ bn3m, const float* __restrict__ bn3v,
    float* __restrict__ Bf)
{
  __shared__ float aS[16 * 3 * 116];
  __shared__ float wS[48 * 16 * 9];
  const int tid = threadIdx.x;
  const int bl = blockIdx.x / 510;
  const int t = blockIdx.x - bl * 510;

  for (int ocg = 0; ocg < 2; ++ocg) {
    float accA[11], accB[11];
#pragma unroll
    for (int i = 0; i < 11; ++i) { accA[i] = 0.f; accB[i] = 0.f; }
    for (int icc = 0; icc < 3; ++icc) {
      __syncthreads();
      for (int idx = tid; idx < 16 * 3 * 116; idx += 256) {
        int cl = idx / 348, rem = idx - cl * 348;
        int rr = rem / 116, cc = rem - rr * 116;
        int w = cc - 1;
        float v = 0.f;
        if (w >= 0 && w < 114) v = A[((bl * 48 + icc * 16 + cl) * 512 + t + rr) * 114 + w];
        aS[idx] = v;
      }
      for (int idx = tid; idx < 48 * 16 * 9; idx += 256) {
        int ocl = idx / 144, rem = idx - ocl * 144;
        wS[idx] = c3w[((ocg * 48 + ocl) * 48 + icc * 16) * 9 + rem];
      }
      __syncthreads();
      for (int i = 0; i < 11; ++i) {
        int oidx = tid + i * 256;
        if (oidx >= 2736) break;
        int ocl = oidx / 57, wp = oidx - ocl * 57;
        int w0 = 2 * wp;
        float a0 = accA[i], a1 = accB[i];
        const float* wb = wS + ocl * 144;
        for (int icl = 0; icl < 16; ++icl) {
#pragma unroll
          for (int a = 0; a < 3; ++a) {
            const float* xr = aS + (icl * 3 + a) * 116 + w0;
            float x0 = xr[0], x1 = xr[1], x2 = xr[2], x3 = xr[3];
            float wA = wb[icl * 9 + a * 3 + 0];
            float wB = wb[icl * 9 + a * 3 + 1];
            float wC = wb[icl * 9 + a * 3 + 2];
            a0 = fmaf(x0, wA, a0); a0 = fmaf(x1, wB, a0); a0 = fmaf(x2, wC, a0);
            a1 = fmaf(x1, wA, a1); a1 = fmaf(x2, wB, a1); a1 = fmaf(x3, wC, a1);
          }
        }
        accA[i] = a0; accB[i] = a1;
      }
    }
    for (int i = 0; i < 11; ++i) {
      int oidx = tid + i * 256;
      if (oidx >= 2736) break;
      int ocl = oidx / 57, wp = oidx - ocl * 57;
      int oc = ocg * 48 + ocl;
      float sc = bn3g[oc] * rsqrtf(bn3v[oc] + 1e-5f);
      float sh = bn3b[oc] - bn3m[oc] * sc;
      float v0 = fmaxf((accA[i] + c3b[oc]) * sc + sh, 0.f);
      float v1 = fmaxf((accB[i] + c3b[oc]) * sc + sh, 0.f);
      Bf[(size_t)(bl * 510 + t) * 5472 + oc * 57 + wp] = fmaxf(v0, v1);
    }
  }
}

// ---------------------------------------------------------------------------
// K3: fp32 NT GEMM  C[M,N] = A * B^T + bias. (FC only)
// ---------------------------------------------------------------------------
__global__ __launch_bounds__(256) void gemm_nt(
    const float* __restrict__ Am, const float* __restrict__ Bm,
    const float* __restrict__ bias, float* __restrict__ C,
    int M, int N, int K, int lda, int ldb, int ldc)
{
  __shared__ float As[64 * 33];
  __shared__ float Bs[64 * 33];
  const int tid = threadIdx.x;
  const int m0 = blockIdx.x * 64, n0 = blockIdx.y * 64;
  const int tx = tid & 15, ty = tid >> 4;
  const int kq = (tid & 7) * 4, rw = tid >> 3;
  float acc[4][4];
#pragma unroll
  for (int i = 0; i < 4; ++i)
#pragma unroll
    for (int j = 0; j < 4; ++j) acc[i][j] = 0.f;

  for (int k0 = 0; k0 < K; k0 += 32) {
    int m1 = m0 + rw, m2 = m1 + 32;
    float4 va = make_float4(0.f, 0.f, 0.f, 0.f), vb = va;
    if (m1 < M) va = *(const float4*)(Am + (size_t)m1 * lda + k0 + kq);
    if (m2 < M) vb = *(const float4*)(Am + (size_t)m2 * lda + k0 + kq);
    float4 wa = *(const float4*)(Bm + (size_t)(n0 + rw) * ldb + k0 + kq);
    float4 wb = *(const float4*)(Bm + (size_t)(n0 + rw + 32) * ldb + k0 + kq);
    As[rw * 33 + kq + 0] = va.x; As[rw * 33 + kq + 1] = va.y;
    As[rw * 33 + kq + 2] = va.z; As[rw * 33 + kq + 3] = va.w;
    As[(rw + 32) * 33 + kq + 0] = vb.x; As[(rw + 32) * 33 + kq + 1] = vb.y;
    As[(rw + 32) * 33 + kq + 2] = vb.z; As[(rw + 32) * 33 + kq + 3] = vb.w;
    Bs[rw * 33 + kq + 0] = wa.x; Bs[rw * 33 + kq + 1] = wa.y;
    Bs[rw * 33 + kq + 2] = wa.z; Bs[rw * 33 + kq + 3] = wa.w;
    Bs[(rw + 32) * 33 + kq + 0] = wb.x; Bs[(rw + 32) * 33 + kq + 1] = wb.y;
    Bs[(rw + 32) * 33 + kq + 2] = wb.z; Bs[(rw + 32) * 33 + kq + 3] = wb.w;
    __syncthreads();
#pragma unroll 8
    for (int k = 0; k < 32; ++k) {
      float av[4], bv[4];
#pragma unroll
      for (int i = 0; i < 4; ++i) av[i] = As[(ty * 4 + i) * 33 + k];
#pragma unroll
      for (int j = 0; j < 4; ++j) bv[j] = Bs[(tx * 4 + j) * 33 + k];
#pragma unroll
      for (int i = 0; i < 4; ++i)
#pragma unroll
        for (int j = 0; j < 4; ++j) acc[i][j] = fmaf(av[i], bv[j], acc[i][j]);
    }
    __syncthreads();
  }
#pragma unroll
  for (int i = 0; i < 4; ++i) {
    int m = m0 + ty * 4 + i;
    if (m >= M) continue;
#pragma unroll
    for (int j = 0; j < 4; ++j) {
      int n = n0 + tx * 4 + j;
      C[(size_t)m * ldc + n] = acc[i][j] + bias[n];
    }
  }
}

// ---------------------------------------------------------------------------
__global__ void init_state(ull* __restrict__ h1g, ull* __restrict__ h2g,
                           unsigned* __restrict__ bar) {
  int gid = blockIdx.x * 256 + threadIdx.x;
  if (gid < 12288) { at_store(h1g + gid, 0ull); at_store(h2g + gid, 0ull); }
  if (gid < 160)
    __hip_atomic_store(bar + gid, 0u, __ATOMIC_RELAXED, __HIP_MEMORY_SCOPE_AGENT);
}

// ---------------------------------------------------------------------------
// K6: persistent LSTM, register-resident weights (structure = round 4).
// ---------------------------------------------------------------------------
__global__ __launch_bounds__(256, 1) void lstm_kernel(
    const float* __restrict__ aco,   // [16][510][768]
    const float* __restrict__ whh0,  // [3072][768]
    const float* __restrict__ wih0,  // [3072][944]
    const float* __restrict__ wih1,  // [3072][768]
    const float* __restrict__ whh1,  // [3072][768]
    const float* __restrict__ bih0, const float* __restrict__ bhh0,
    const float* __restrict__ bih1, const float* __restrict__ bhh1,
    const float* __restrict__ pw,    // [440][768]
    const float* __restrict__ pb,
    const float* __restrict__ emb,   // [5][2]
    ull* __restrict__ h1g,           // [2][16][384] packed pairs
    ull* __restrict__ h2g,
    ull* __restrict__ prevg,         // [16][88] packed emb pairs
    unsigned* __restrict__ bar,
    float* __restrict__ out)         // [16][510][440]
{
  __shared__ float hs[16 * 772];     // chunked [s][b][48], stride 772
  __shared__ float prevs[16 * 177];  // chunked [s][b][11], stride 177
  __shared__ float zl[16 * 17];      // [row][b]
  __shared__ float harr[64];
  __shared__ float embS[10];
  const int tid = threadIdx.x;
  const int s = tid & 15;            // k-chunk
  const int r = tid >> 4;            // gate-row (dots) / batch (staging)
  const int uB = blockIdx.x * 4;
  const int j = (r >> 2) * 768 + uB + (r & 3);

  // ---- one-time register weight load ----
  float wx[48], w0[48], w1[48], w2[48], wp[11], pwr[48];
  {
    const float* p = wih0 + (size_t)j * 944 + 48 * s;
#pragma unroll
    for (int i = 0; i < 48; i += 4) {
      float4 v = *(const float4*)(p + i);
      wx[i] = v.x; wx[i+1] = v.y; wx[i+2] = v.z; wx[i+3] = v.w;
    }
    p = whh0 + (size_t)j * 768 + 48 * s;
#pragma unroll
    for (int i = 0; i < 48; i += 4) {
      float4 v = *(const float4*)(p + i);
      w0[i] = v.x; w0[i+1] = v.y; w0[i+2] = v.z; w0[i+3] = v.w;
    }
    p = wih1 + (size_t)j * 768 + 48 * s;
#pragma unroll
    for (int i = 0; i < 48; i += 4) {
      float4 v = *(const float4*)(p + i);
      w1[i] = v.x; w1[i+1] = v.y; w1[i+2] = v.z; w1[i+3] = v.w;
    }
    p = whh1 + (size_t)j * 768 + 48 * s;
#pragma unroll
    for (int i = 0; i < 48; i += 4) {
      float4 v = *(const float4*)(p + i);
      w2[i] = v.x; w2[i+1] = v.y; w2[i+2] = v.z; w2[i+3] = v.w;
    }
    const float* pp = wih0 + (size_t)j * 944 + 768 + 11 * s;
#pragma unroll
    for (int i = 0; i < 11; ++i) wp[i] = pp[i];
  }
  const bool pv = (blockIdx.x < 88) && (r < 5);
  const int prow = blockIdx.x * 5 + r;
  float pbv = 0.f;
  if (pv) {
    const float* p = pw + (size_t)prow * 768 + 48 * s;
#pragma unroll
    for (int i = 0; i < 48; i += 4) {
      float4 v = *(const float4*)(p + i);
      pwr[i] = v.x; pwr[i+1] = v.y; pwr[i+2] = v.z; pwr[i+3] = v.w;
    }
    pbv = pb[prow];
  } else {
#pragma unroll
    for (int i = 0; i < 48; ++i) pwr[i] = 0.f;
  }
  // cell-thread constants (tid<64: ul = tid>>4, b = tid&15)
  float bl1[4], bl2[4], c1 = 0.f, c2 = 0.f;
  if (tid < 64) {
    int ul = tid >> 4;
#pragma unroll
    for (int g = 0; g < 4; ++g) {
      int jj = g * 768 + uB + ul;
      bl1[g] = bih0[jj] + bhh0[jj];
      bl2[g] = bih1[jj] + bhh1[jj];
    }
  }
  if (tid < 10) embS[tid] = emb[tid];

  unsigned nb = 0;
  const unsigned NG = gridDim.x;

  for (int t = 0; t < 510; ++t) {
    const int wbuf = t & 1, rbuf = wbuf ^ 1;
    // ============ PH1a: stage x(t), x-dot ============
    {
      const float* xr = aco + ((size_t)r * 510 + t) * 768 + 48 * s;
      float* dst = hs + s * 772 + r * 48;
#pragma unroll
      for (int i = 0; i < 48; i += 4) *(float4*)(dst + i) = *(const float4*)(xr + i);
    }
    __syncthreads();
    for (int b = 0; b < 16; ++b) {
      float p; CDOT48(wx, hs + s * 772 + b * 48, p);
      p = red16(p);
      if (s == 0) zl[r * 17 + b] = p;
    }
    __syncthreads();
    // ============ PH1b: stage h1(t-1) + prevs, recurrent dot ============
    STAGE_H(h1g + rbuf * 6144);
    if (t == 0) {
      float* pd = prevs + s * 177 + r * 11;
#pragma unroll
      for (int i = 0; i < 11; ++i) pd[i] = 0.f;
    } else {
      const ull* pg = prevg + r * 88;
      float* pd = prevs + s * 177 + r * 11;
      int d0 = 11 * s;
#pragma unroll
      for (int i = 0; i < 11; ++i) {
        int d = d0 + i;
        float2 e = unpack2(at_load(pg + (d >> 1)));
        pd[i] = (d & 1) ? e.y : e.x;
      }
    }
    __syncthreads();
    for (int b = 0; b < 16; ++b) {
      float p; CDOT48(w0, hs + s * 772 + b * 48, p);
      const float* pvv = prevs + s * 177 + b * 11;
#pragma unroll
      for (int i = 0; i < 11; ++i) p = fmaf(wp[i], pvv[i], p);
      p = red16(p);
      if (s == 0) zl[r * 17 + b] += p;
    }
    __syncthreads();
    if (tid < 64) {
      int ul = tid >> 4, bb = tid & 15;
      float zi = zl[(0 * 4 + ul) * 17 + bb] + bl1[0];
      float zf = zl[(1 * 4 + ul) * 17 + bb] + bl1[1];
      float zg = zl[(2 * 4 + ul) * 17 + bb] + bl1[2];
      float zo = zl[(3 * 4 + ul) * 17 + bb] + bl1[3];
      c1 = sigf(zf) * c1 + sigf(zi) * tanhf(zg);
      harr[tid] = sigf(zo) * tanhf(c1);
    }
    __syncthreads();
    if (tid < 32) {
      int q = tid >> 4, bb = tid & 15;
      at_store(h1g + wbuf * 6144 + bb * 384 + blockIdx.x * 2 + q,
               pack2(harr[(2 * q) * 16 + bb], harr[(2 * q + 1) * 16 + bb]));
    }
    ++nb; gbar(bar, nb, NG);
    // ============ PH2: h2 cell ============
    STAGE_H(h1g + wbuf * 6144);
    __syncthreads();
    for (int b = 0; b < 16; ++b) {
      float p; CDOT48(w1, hs + s * 772 + b * 48, p);
      p = red16(p);
      if (s == 0) zl[r * 17 + b] = p;
    }
    __syncthreads();
    STAGE_H(h2g + rbuf * 6144);
    __syncthreads();
    for (int b = 0; b < 16; ++b) {
      float p; CDOT48(w2, hs + s * 772 + b * 48, p);
      p = red16(p);
      if (s == 0) zl[r * 17 + b] += p;
    }
    __syncthreads();
    if (tid < 64) {
      int ul = tid >> 4, bb = tid & 15;
      float zi = zl[(0 * 4 + ul) * 17 + bb] + bl2[0];
      float zf = zl[(1 * 4 + ul) * 17 + bb] + bl2[1];
      float zg = zl[(2 * 4 + ul) * 17 + bb] + bl2[2];
      float zo = zl[(3 * 4 + ul) * 17 + bb] + bl2[3];
      c2 = sigf(zf) * c2 + sigf(zi) * tanhf(zg);
      harr[tid] = sigf(zo) * tanhf(c2);
    }
    __syncthreads();
    if (tid < 32) {
      int q = tid >> 4, bb = tid & 15;
      at_store(h2g + wbuf * 6144 + bb * 384 + blockIdx.x * 2 + q,
               pack2(harr[(2 * q) * 16 + bb], harr[(2 * q + 1) * 16 + bb]));
    }
    ++nb; gbar(bar, nb, NG);
    // ============ PH3: projection + argmax (blocks < 88, pitch each) ====
    if (blockIdx.x < 88) {
      STAGE_H(h2g + wbuf * 6144);
      __syncthreads();
      for (int b = 0; b < 16; ++b) {
        float p; CDOT48(pwr, hs + s * 772 + b * 48, p);
        p = red16(p);
        if (pv && s == 0) {
          float lg = p + pbv;
          out[((size_t)b * 510 + t) * 440 + prow] = lg;
          zl[r * 17 + b] = lg;
        }
      }
      __syncthreads();
      if (tid < 16) {
        float best = zl[0 * 17 + tid]; int bi = 0;
#pragma unroll
        for (int c = 1; c < 5; ++c) {
          float v = zl[c * 17 + tid];
          if (v > best) { best = v; bi = c; }
        }
        at_store(prevg + tid * 88 + blockIdx.x, pack2(embS[bi * 2], embS[bi * 2 + 1]));
      }
    }
    ++nb; gbar(bar, nb, NG);
  }
}

// ---------------------------------------------------------------------------
extern "C" void kernel_launch(void* const* d_in, const int* in_sizes, int n_in,
                              void* d_out, int out_size, void* d_ws, size_t ws_size,
                              hipStream_t stream) {
  (void)in_sizes; (void)n_in; (void)out_size;
  const float* mel  = (const float*)d_in[0];
  const float* c1w  = (const float*)d_in[1];
  const float* c1b  = (const float*)d_in[2];
  const float* c2w  = (const float*)d_in[3];
  const float* c2b  = (const float*)d_in[4];
  const float* c3w  = (const float*)d_in[5];
  const float* c3b  = (const float*)d_in[6];
  const float* bn1g = (const float*)d_in[7];
  const float* bn1b = (const float*)d_in[8];
  const float* bn1m = (const float*)d_in[9];
  const float* bn1v = (const float*)d_in[10];
  const float* bn2g = (const float*)d_in[11];
  const float* bn2b = (const float*)d_in[12];
  const float* bn2m = (const float*)d_in[13];
  const float* bn2v = (const float*)d_in[14];
  const float* bn3g = (const float*)d_in[15];
  const float* bn3b = (const float*)d_in[16];
  const float* bn3m = (const float*)d_in[17];
  const float* bn3v = (const float*)d_in[18];
  const float* fcw  = (const float*)d_in[19];
  const float* fcb  = (const float*)d_in[20];
  const float* wih0 = (const float*)d_in[21];
  const float* whh0 = (const float*)d_in[22];
  const float* bih0 = (const float*)d_in[23];
  const float* bhh0 = (const float*)d_in[24];
  const float* wih1 = (const float*)d_in[25];
  const float* whh1 = (const float*)d_in[26];
  const float* bih1 = (const float*)d_in[27];
  const float* bhh1 = (const float*)d_in[28];
  const float* pw   = (const float*)d_in[29];
  const float* pb   = (const float*)d_in[30];
  const float* emb  = (const float*)d_in[31];

  float* ws = (float*)d_ws;
  float* outp = (float*)d_out;

  const size_t ST_ULL = 12288ull + 12288ull + 1408ull;
  int CB = 1;
  for (int cb = 4; cb >= 1; cb >>= 1) {
    size_t need = (ACO_FL + (size_t)cb * 48 * 512 * 114 + (size_t)cb * 510 * 5472) * 4
                + ST_ULL * 8 + 1024;
    if (ws_size >= need) { CB = cb; break; }
  }
  const int nchunks = 16 / CB;
  const size_t A_FL  = (size_t)CB * 48 * 512 * 114;
  const size_t BF_FL = (size_t)CB * 510 * 5472;

  float* aco = ws;
  float* Ac  = ws + ACO_FL;
  float* Bfc = Ac + A_FL;
  ull* h1g   = (ull*)(Bfc + BF_FL);
  ull* h2g   = h1g + 12288;
  ull* prevg = h2g + 12288;
  unsigned* bar = (unsigned*)(prevg + 1408);

  for (int ch = 0; ch < nchunks; ++ch) {
    int b0 = ch * CB;
    hipLaunchKernelGGL(conv12_kernel, dim3(CB * 512), dim3(256), 0, stream,
                       mel, c1w, c1b, bn1g, bn1b, bn1m, bn1v,
                       c2w, c2b, bn2g, bn2b, bn2m, bn2v, Ac, b0);
    hipLaunchKernelGGL(conv3_kernel, dim3(CB * 510), dim3(256), 0, stream,
                       Ac, c3w, c3b, bn3g, bn3b, bn3m, bn3v, Bfc);
    int M = CB * 510;
    hipLaunchKernelGGL(gemm_nt, dim3((M + 63) / 64, 12), dim3(256), 0, stream,
                       Bfc, fcw, fcb, aco + (size_t)b0 * 510 * 768,
                       M, 768, 5472, 5472, 5472, 768);
  }
  hipLaunchKernelGGL(init_state, dim3(48), dim3(256), 0, stream, h1g, h2g, bar);

  {
    void* args[] = {
      (void*)&aco, (void*)&whh0, (void*)&wih0, (void*)&wih1, (void*)&whh1,
      (void*)&bih0, (void*)&bhh0, (void*)&bih1, (void*)&bhh1,
      (void*)&pw, (void*)&pb, (void*)&emb,
      (void*)&h1g, (void*)&h2g, (void*)&prevg, (void*)&bar, (void*)&outp
    };
    hipError_t e = hipLaunchCooperativeKernel((const void*)lstm_kernel,
                                              dim3(192), dim3(256), args, 0, stream);
    if (e != hipSuccess) {
      (void)hipGetLastError();
      hipLaunchKernelGGL(lstm_kernel, dim3(192), dim3(256), 0, stream,
                         aco, whh0, wih0, wih1, whh1, bih0, bhh0, bih1, bhh1,
                         pw, pb, emb, h1g, h2g, prevg, bar, outp);
    }
  }
}